// Round 2
// baseline (447.837 us; speedup 1.0000x reference)
//
#include <hip/hip_runtime.h>
#include <math.h>

// Dims (fixed by the problem)
constexpr int Bb = 2, Nn = 512, Tt = 12, Ee = 128, Hh = 8, Dd = 16;
constexpr int NTOK   = Bb * Nn * Tt;      // 12288 tokens
constexpr int PROJ   = NTOK * Ee;         // 1572864 floats per [B,N,T,E] tensor
constexpr int SLICES = Bb * Hh * Tt;      // 192 attention slices
constexpr int MT     = 32;                // tokens per GEMM block

// Workspace layout (floats):
//   proj[0..6]: Qf,Kf,Vf,Qs,Ks,Vs,Qfs  in head-major [B,H,T,N,D]  (7 * 6MB)
//   ctx[0..3] : attention outputs      in token-major [B,N,T,E]   (4 * 6MB)

struct PtrPack { const float* x[6]; const float* W[6]; };

__device__ __forceinline__ void fma4(float4& a, float s, float4 w) {
  a.x = fmaf(s, w.x, a.x); a.y = fmaf(s, w.y, a.y);
  a.z = fmaf(s, w.z, a.z); a.w = fmaf(s, w.w, a.w);
}
__device__ __forceinline__ float dot4(float4 a, float4 b, float acc) {
  acc = fmaf(a.x, b.x, acc); acc = fmaf(a.y, b.y, acc);
  acc = fmaf(a.z, b.z, acc); acc = fmaf(a.w, b.w, acc);
  return acc;
}
__device__ __forceinline__ void scl4(float4& a, float s) {
  a.x *= s; a.y *= s; a.z *= s; a.w *= s;
}

// ---------------------------------------------------------------------------
// Kernel P: y = x @ W for 6 inputs; writes head-major [B,H,T,N,D].
// type 3 (Qs) additionally writes Qfs = Kj[n]*(Qs - Qs^2/(Vfp[n]+1e-5)).
// LDS-free: W rows stream through L1/L2 (re-read by all blocks, hot);
// x rows are 32-lane-uniform reads.
// ---------------------------------------------------------------------------
__global__ __launch_bounds__(256) void proj_kernel(
    PtrPack pp, const float* __restrict__ Kj, const float* __restrict__ Vfp,
    float* __restrict__ proj)
{
  const int ty  = blockIdx.y;           // which projection 0..5
  const int tid = threadIdx.x;
  const float* __restrict__ W = pp.W[ty];
  const float* __restrict__ x = pp.x[ty];
  const int tk0 = blockIdx.x * MT;

  const int c4 = (tid & 31) * 4;   // output col base (0..124)
  const int tg = tid >> 5;         // token group 0..7 -> 4 tokens each
  const float* __restrict__ xb = x + (size_t)(tk0 + tg * 4) * Ee;

  float4 acc[4];
  #pragma unroll
  for (int i = 0; i < 4; ++i) acc[i] = make_float4(0.f, 0.f, 0.f, 0.f);

  for (int k = 0; k < Ee; k += 4) {
    float4 w0 = *(const float4*)&W[(size_t)(k + 0) * Ee + c4];
    float4 w1 = *(const float4*)&W[(size_t)(k + 1) * Ee + c4];
    float4 w2 = *(const float4*)&W[(size_t)(k + 2) * Ee + c4];
    float4 w3 = *(const float4*)&W[(size_t)(k + 3) * Ee + c4];
    #pragma unroll
    for (int tt = 0; tt < 4; ++tt) {
      float4 xv = *(const float4*)&xb[(size_t)tt * Ee + k];
      fma4(acc[tt], xv.x, w0); fma4(acc[tt], xv.y, w1);
      fma4(acc[tt], xv.z, w2); fma4(acc[tt], xv.w, w3);
    }
  }

  const int h = c4 >> 4, d0 = c4 & 15;
  #pragma unroll
  for (int tt = 0; tt < 4; ++tt) {
    const int tk = tk0 + tg * 4 + tt;
    const int b  = tk / (Nn * Tt);
    const int rm = tk - b * (Nn * Tt);
    const int n  = rm / Tt;
    const int t  = rm - n * Tt;
    const size_t off = ((((size_t)b * Hh + h) * Tt + t) * Nn + n) * Dd + d0;
    *(float4*)&proj[(size_t)ty * PROJ + off] = acc[tt];
    if (ty == 3) {  // FlowSpeed nonlinearity -> Qfs (proj slot 6)
      const float kj  = Kj[n];
      const float inv = 1.0f / (Vfp[n] + 1e-5f);
      float4 q = acc[tt], g;
      g.x = kj * (q.x - q.x * q.x * inv);
      g.y = kj * (q.y - q.y * q.y * inv);
      g.z = kj * (q.z - q.z * q.z * inv);
      g.w = kj * (q.w - q.w * q.w * inv);
      *(float4*)&proj[(size_t)6 * PROJ + off] = g;
    }
  }
}

// ---------------------------------------------------------------------------
// Kernel A: flash attention, LDS-free, 1 q-row per thread.
// K/V row reads are wave-uniform -> broadcast/scalar loads from L1/L2.
// Types 0,2,3 (ff,sf,ss): raw-exp softmax (no max tracking) — operands are
//   16-dim dots of ~unit-norm projection rows, |s*log2e| < ~25 << 128
//   (fp32 exp2 overflow), so exp2(s)/sum(exp2(s)) is safe and exact.
// Type 1 (fs): B-side Qfs has 1/(Vfp+1e-5) blowup (scores can reach ~1e3+)
//   -> online chunk-8 max-tracked flash.
// ---------------------------------------------------------------------------
__global__ __launch_bounds__(256) void attn_kernel(
    const float* __restrict__ proj, float* __restrict__ ctx)
{
  const int slice = blockIdx.x;   // (b*H+h)*T+t
  const int ty    = blockIdx.y;   // 0:ff 1:fs 2:sf 3:ss
  const int half  = blockIdx.z;   // q-row half
  const int aidx[4] = {0, 1, 4, 3};
  const int bidx[4] = {1, 6, 0, 4};
  const int vidx[4] = {2, 2, 5, 5};
  const size_t base = (size_t)slice * (Nn * Dd);
  const float* __restrict__ Aq = proj + (size_t)aidx[ty] * PROJ + base;
  const float* __restrict__ Bk = proj + (size_t)bidx[ty] * PROJ + base;
  const float* __restrict__ Vv = proj + (size_t)vidx[ty] * PROJ + base;
  const int r = half * 256 + threadIdx.x;

  // scale = 1/sqrt(D); fold log2(e)*scale into q so p = exp2(s)
  const float SC = 0.25f * 1.4426950408889634f;
  float4 q[4];
  #pragma unroll
  for (int i = 0; i < 4; ++i) {
    q[i] = *(const float4*)&Aq[(size_t)r * Dd + i * 4];
    scl4(q[i], SC);
  }

  float4 o[4];
  #pragma unroll
  for (int i = 0; i < 4; ++i) o[i] = make_float4(0.f, 0.f, 0.f, 0.f);
  float l = 0.f;

  if (ty != 1) {
    // ---- raw-exp path (no max subtraction needed) ----
    for (int m0 = 0; m0 < Nn; m0 += 8) {
      #pragma unroll
      for (int j = 0; j < 8; ++j) {
        const float4* kp = (const float4*)&Bk[(size_t)(m0 + j) * Dd];
        float4 k0 = kp[0], k1 = kp[1], k2 = kp[2], k3 = kp[3];
        float s = 0.f;
        s = dot4(q[0], k0, s); s = dot4(q[1], k1, s);
        s = dot4(q[2], k2, s); s = dot4(q[3], k3, s);
        const float p = exp2f(s);
        l += p;
        const float4* vp = (const float4*)&Vv[(size_t)(m0 + j) * Dd];
        fma4(o[0], p, vp[0]); fma4(o[1], p, vp[1]);
        fma4(o[2], p, vp[2]); fma4(o[3], p, vp[3]);
      }
    }
  } else {
    // ---- online max-tracked path (chunk 8) ----
    float mx = -INFINITY;
    for (int m0 = 0; m0 < Nn; m0 += 8) {
      float s[8];
      #pragma unroll
      for (int j = 0; j < 8; ++j) {
        const float4* kp = (const float4*)&Bk[(size_t)(m0 + j) * Dd];
        float t = 0.f;
        t = dot4(q[0], kp[0], t); t = dot4(q[1], kp[1], t);
        t = dot4(q[2], kp[2], t); t = dot4(q[3], kp[3], t);
        s[j] = t;
      }
      float cm = s[0];
      #pragma unroll
      for (int j = 1; j < 8; ++j) cm = fmaxf(cm, s[j]);
      const float nm = fmaxf(mx, cm);
      const float f  = exp2f(mx - nm);   // exp2(-inf)=0 on first chunk
      mx = nm;
      l *= f;
      #pragma unroll
      for (int i = 0; i < 4; ++i) scl4(o[i], f);
      #pragma unroll
      for (int j = 0; j < 8; ++j) {
        const float p = exp2f(s[j] - mx);
        l += p;
        const float4* vp = (const float4*)&Vv[(size_t)(m0 + j) * Dd];
        fma4(o[0], p, vp[0]); fma4(o[1], p, vp[1]);
        fma4(o[2], p, vp[2]); fma4(o[3], p, vp[3]);
      }
    }
  }

  const float inv = 1.0f / l;
  const int b = slice / (Hh * Tt);
  const int h = (slice / Tt) % Hh;
  const int t = slice % Tt;
  float* __restrict__ outp = ctx + (size_t)ty * PROJ;
  const size_t row = (((size_t)b * Nn + r) * Tt + t) * Ee + h * Dd;
  #pragma unroll
  for (int i = 0; i < 4; ++i) {
    float4 v = o[i]; scl4(v, inv);
    *(float4*)&outp[row + i * 4] = v;
  }
}

// ---------------------------------------------------------------------------
// Kernel O: out[ty] = ctx[ty] @ Wout + bout   (token-major in and out)
// LDS-free, same structure as proj.
// ---------------------------------------------------------------------------
__global__ __launch_bounds__(256) void out_kernel(
    const float* __restrict__ ctx, const float* __restrict__ Wout,
    const float* __restrict__ bout, float* __restrict__ out)
{
  const int ty  = blockIdx.y;
  const int tid = threadIdx.x;
  const float* __restrict__ x = ctx + (size_t)ty * PROJ;
  const int tk0 = blockIdx.x * MT;

  const int c4 = (tid & 31) * 4;
  const int tg = tid >> 5;
  const float* __restrict__ xb = x + (size_t)(tk0 + tg * 4) * Ee;

  float4 acc[4];
  #pragma unroll
  for (int i = 0; i < 4; ++i) acc[i] = make_float4(0.f, 0.f, 0.f, 0.f);

  for (int k = 0; k < Ee; k += 4) {
    float4 w0 = *(const float4*)&Wout[(size_t)(k + 0) * Ee + c4];
    float4 w1 = *(const float4*)&Wout[(size_t)(k + 1) * Ee + c4];
    float4 w2 = *(const float4*)&Wout[(size_t)(k + 2) * Ee + c4];
    float4 w3 = *(const float4*)&Wout[(size_t)(k + 3) * Ee + c4];
    #pragma unroll
    for (int tt = 0; tt < 4; ++tt) {
      float4 xv = *(const float4*)&xb[(size_t)tt * Ee + k];
      fma4(acc[tt], xv.x, w0); fma4(acc[tt], xv.y, w1);
      fma4(acc[tt], xv.z, w2); fma4(acc[tt], xv.w, w3);
    }
  }

  const float4 bv = *(const float4*)&bout[c4];
  #pragma unroll
  for (int tt = 0; tt < 4; ++tt) {
    const int tk = tk0 + tg * 4 + tt;
    float4 r = acc[tt];
    r.x += bv.x; r.y += bv.y; r.z += bv.z; r.w += bv.w;
    *(float4*)&out[(size_t)ty * PROJ + (size_t)tk * Ee + c4] = r;
  }
}

// ---------------------------------------------------------------------------
extern "C" void kernel_launch(void* const* d_in, const int* in_sizes, int n_in,
                              void* d_out, int out_size, void* d_ws, size_t ws_size,
                              hipStream_t stream) {
  const float* fq  = (const float*)d_in[0];
  const float* fk  = (const float*)d_in[1];
  const float* fv  = (const float*)d_in[2];
  const float* sq  = (const float*)d_in[3];
  const float* sk  = (const float*)d_in[4];
  const float* sv  = (const float*)d_in[5];
  const float* WfQ = (const float*)d_in[6];
  const float* WfK = (const float*)d_in[7];
  const float* WfV = (const float*)d_in[8];
  const float* WsQ = (const float*)d_in[9];
  const float* WsK = (const float*)d_in[10];
  const float* WsV = (const float*)d_in[11];
  const float* Kj  = (const float*)d_in[12];
  const float* Vfp = (const float*)d_in[13];
  const float* Wout = (const float*)d_in[14];
  const float* bout = (const float*)d_in[15];

  float* proj = (float*)d_ws;                  // 7 * PROJ floats
  float* ctx  = proj + (size_t)7 * PROJ;       // 4 * PROJ floats

  PtrPack pp;
  pp.x[0] = fq; pp.x[1] = fk; pp.x[2] = fv;
  pp.x[3] = sq; pp.x[4] = sk; pp.x[5] = sv;
  pp.W[0] = WfQ; pp.W[1] = WfK; pp.W[2] = WfV;
  pp.W[3] = WsQ; pp.W[4] = WsK; pp.W[5] = WsV;

  proj_kernel<<<dim3(NTOK / MT, 6), 256, 0, stream>>>(pp, Kj, Vfp, proj);
  attn_kernel<<<dim3(SLICES, 4, 2), 256, 0, stream>>>(proj, ctx);
  out_kernel<<<dim3(NTOK / MT, 4), 256, 0, stream>>>(ctx, Wout, bout, (float*)d_out);
}

// Round 4
// 275.585 us; speedup vs baseline: 1.6250x; 1.6250x over previous
//
#include <hip/hip_runtime.h>
#include <math.h>

// Dims (fixed by the problem)
constexpr int Bb = 2, Nn = 512, Tt = 12, Ee = 128, Hh = 8, Dd = 16;
constexpr int NTOK   = Bb * Nn * Tt;      // 12288 tokens
constexpr int PROJ   = NTOK * Ee;         // 1572864 floats per [B,N,T,E] tensor
constexpr int SLICES = Bb * Hh * Tt;      // 192 attention slices
constexpr int MT     = 32;                // tokens per GEMM block

// Workspace layout (floats):
//   proj[0..6]: Qf,Kf,Vf,Qs,Ks,Vs,Qfs  head-major [B,H,T,N,D]   (7 * 6MB)
//   ctx[0..3] : attention outputs      token-major [B,N,T,E]    (4 * 6MB)

struct PtrPack { const float* x[6]; const float* W[6]; };

typedef __attribute__((ext_vector_type(8)))  short bf16x8;
typedef __attribute__((ext_vector_type(16))) float f32x16;
union FragU { bf16x8 v; unsigned u[4]; };

__device__ __forceinline__ void fma4(float4& a, float s, float4 w) {
  a.x = fmaf(s, w.x, a.x); a.y = fmaf(s, w.y, a.y);
  a.z = fmaf(s, w.z, a.z); a.w = fmaf(s, w.w, a.w);
}

__device__ __forceinline__ unsigned pk_bf16(float a, float b) {
  unsigned r;
  asm("v_cvt_pk_bf16_f32 %0, %1, %2" : "=v"(r) : "v"(a), "v"(b));
  return r;
}

// fp32 -> bf16 hi + bf16 residual-lo fragments (8 elems); combined ~17-bit
// mantissa so 4-term MFMA products carry ~2^-17 relative error.
__device__ __forceinline__ void split_frag(const float e[8], bf16x8& hv, bf16x8& lv) {
  FragU H, L;
  #pragma unroll
  for (int i = 0; i < 4; ++i) {
    const unsigned h = pk_bf16(e[2*i], e[2*i+1]);
    const float h0 = __uint_as_float(h << 16);
    const float h1 = __uint_as_float(h & 0xffff0000u);
    L.u[i] = pk_bf16(e[2*i] - h0, e[2*i+1] - h1);
    H.u[i] = h;
  }
  hv = H.v; lv = L.v;
}

__device__ __forceinline__ bf16x8 cvt_frag(const float e[8]) {
  FragU F;
  #pragma unroll
  for (int i = 0; i < 4; ++i) F.u[i] = pk_bf16(e[2*i], e[2*i+1]);
  return F.v;
}

// ---------------------------------------------------------------------------
// Kernel P (known-good): y = x @ W, head-major out; ty==3 also writes
// Qfs = Kj[n]*(Qs - Qs^2/(Vfp[n]+1e-5)) to slot 6.
// ---------------------------------------------------------------------------
__global__ __launch_bounds__(256) void proj_kernel(
    PtrPack pp, const float* __restrict__ Kj, const float* __restrict__ Vfp,
    float* __restrict__ proj)
{
  __shared__ float Ws[Ee * Ee];   // 64 KB
  __shared__ float Xs[MT * Ee];   // 16 KB
  const int ty  = blockIdx.y;
  const int tid = threadIdx.x;
  const float* __restrict__ W = pp.W[ty];
  const float* __restrict__ x = pp.x[ty];
  const int tk0 = blockIdx.x * MT;

  for (int i = tid * 4; i < Ee * Ee; i += 1024)
    *(float4*)&Ws[i] = *(const float4*)&W[i];
  for (int i = tid * 4; i < MT * Ee; i += 1024)
    *(float4*)&Xs[i] = *(const float4*)&x[(size_t)tk0 * Ee + i];
  __syncthreads();

  const int c4 = (tid & 31) * 4;
  const int tg = tid >> 5;

  float4 acc[4];
  #pragma unroll
  for (int i = 0; i < 4; ++i) acc[i] = make_float4(0.f, 0.f, 0.f, 0.f);

  for (int k = 0; k < Ee; k += 4) {
    float4 w0 = *(const float4*)&Ws[(k + 0) * Ee + c4];
    float4 w1 = *(const float4*)&Ws[(k + 1) * Ee + c4];
    float4 w2 = *(const float4*)&Ws[(k + 2) * Ee + c4];
    float4 w3 = *(const float4*)&Ws[(k + 3) * Ee + c4];
    #pragma unroll
    for (int tt = 0; tt < 4; ++tt) {
      float4 xv = *(const float4*)&Xs[(tg * 4 + tt) * Ee + k];
      fma4(acc[tt], xv.x, w0); fma4(acc[tt], xv.y, w1);
      fma4(acc[tt], xv.z, w2); fma4(acc[tt], xv.w, w3);
    }
  }

  const int h = c4 >> 4, d0 = c4 & 15;
  #pragma unroll
  for (int tt = 0; tt < 4; ++tt) {
    const int tk = tk0 + tg * 4 + tt;
    const int b  = tk / (Nn * Tt);
    const int rm = tk - b * (Nn * Tt);
    const int n  = rm / Tt;
    const int t  = rm - n * Tt;
    const size_t off = ((((size_t)b * Hh + h) * Tt + t) * Nn + n) * Dd + d0;
    *(float4*)&proj[(size_t)ty * PROJ + off] = acc[tt];
    if (ty == 3) {
      const float kj  = Kj[n];
      const float inv = 1.0f / (Vfp[n] + 1e-5f);
      float4 q = acc[tt], g;
      g.x = kj * (q.x - q.x * q.x * inv);
      g.y = kj * (q.y - q.y * q.y * inv);
      g.z = kj * (q.z - q.z * q.z * inv);
      g.w = kj * (q.w - q.w * q.w * inv);
      *(float4*)&proj[(size_t)6 * PROJ + off] = g;
    }
  }
}

// ---------------------------------------------------------------------------
// Kernel A: MFMA flash attention.  Block = 512 thr (8 waves) = one
// (slice,type); wave owns 64 q-rows (2 q-tiles of 32).
// QK^T swapped (A=keys, B=queries): S[r] = s[k(r,hi), q=lane&31],
//   k(r,hi) = (r&3) + 8*(r>>2) + 4*hi.  Full 4-term bf16 hi/lo split ->
//   ~2^-17-relative logits.
// ty==1 (fs): logits can reach ~1e5 (Vfp+1e-5 blowup), so run a PASS-1 over
//   all keys with the SAME 4-term MFMA to get the exact row max of the
//   values pass-2 will recompute bitwise-identically -> p = exp2(S-m) <= 1,
//   no overflow (round-3 NaN was a bf16-accuracy max underestimating by
//   hundreds of exp2 units).  Other types: m=0 raw exp2 (logits <= ~25).
// PV: P repacked to the A-fragment via cvt_pk pairs + half-swap
//   (shfl_xor(32) + select), V as B-fragment (col = d, lanes 16-31 are
//   ignored duplicates).
// ---------------------------------------------------------------------------
__global__ __launch_bounds__(512) void attn_mfma_kernel(
    const float* __restrict__ proj, float* __restrict__ ctx)
{
  const int slice = blockIdx.x;
  const int ty    = blockIdx.y;
  const int aidx[4] = {0, 1, 4, 3};
  const int bidx[4] = {1, 6, 0, 4};
  const int vidx[4] = {2, 2, 5, 5};
  const size_t base = (size_t)slice * (Nn * Dd);
  const float* __restrict__ Aq = proj + (size_t)aidx[ty] * PROJ + base;  // queries
  const float* __restrict__ Bk = proj + (size_t)bidx[ty] * PROJ + base;  // keys
  const float* __restrict__ Vv = proj + (size_t)vidx[ty] * PROJ + base;

  const int tid  = threadIdx.x;
  const int wave = tid >> 6;
  const int lane = tid & 63;
  const int hi   = lane >> 5;
  const int ql   = lane & 31;
  const int q0   = wave * 64;
  const int d15  = ql & 15;

  const float SC = 0.25f * 1.4426950408889634f;  // 1/sqrt(D) * log2(e)

  // Q fragments (B-operand): lane(ql,hi) holds Q[q0+qt*32+ql][hi*8 + j]
  bf16x8 qh[2], qlo[2];
  #pragma unroll
  for (int qt = 0; qt < 2; ++qt) {
    const int qrow = q0 + qt * 32 + ql;
    const float4 a = *(const float4*)&Aq[qrow * Dd + hi * 8];
    const float4 b = *(const float4*)&Aq[qrow * Dd + hi * 8 + 4];
    float e[8] = {a.x*SC, a.y*SC, a.z*SC, a.w*SC, b.x*SC, b.y*SC, b.z*SC, b.w*SC};
    split_frag(e, qh[qt], qlo[qt]);
  }

  // -------- pass 1 (fs only): exact row max of the pass-2 S values --------
  float m_[2] = {0.0f, 0.0f};
  if (ty == 1) {
    float mx[2] = {-1e30f, -1e30f};
    for (int kc = 0; kc < Nn; kc += 32) {
      const int krow = kc + ql;
      const float4 ka = *(const float4*)&Bk[krow * Dd + hi * 8];
      const float4 kb = *(const float4*)&Bk[krow * Dd + hi * 8 + 4];
      float ke[8] = {ka.x, ka.y, ka.z, ka.w, kb.x, kb.y, kb.z, kb.w};
      bf16x8 kh, kl;
      split_frag(ke, kh, kl);
      #pragma unroll
      for (int qt = 0; qt < 2; ++qt) {
        f32x16 S;
        #pragma unroll
        for (int r = 0; r < 16; ++r) S[r] = 0.0f;
        S = __builtin_amdgcn_mfma_f32_32x32x16_bf16(kh, qh[qt],  S, 0, 0, 0);
        S = __builtin_amdgcn_mfma_f32_32x32x16_bf16(kh, qlo[qt], S, 0, 0, 0);
        S = __builtin_amdgcn_mfma_f32_32x32x16_bf16(kl, qh[qt],  S, 0, 0, 0);
        S = __builtin_amdgcn_mfma_f32_32x32x16_bf16(kl, qlo[qt], S, 0, 0, 0);
        #pragma unroll
        for (int r = 0; r < 16; ++r) mx[qt] = fmaxf(mx[qt], S[r]);
      }
    }
    #pragma unroll
    for (int qt = 0; qt < 2; ++qt)
      m_[qt] = fmaxf(mx[qt], __shfl_xor(mx[qt], 32));
  }

  // -------- pass 2: softmax-weighted PV --------
  f32x16 o[2];
  float  l_[2] = {0.0f, 0.0f};
  #pragma unroll
  for (int qt = 0; qt < 2; ++qt)
    #pragma unroll
    for (int r = 0; r < 16; ++r) o[qt][r] = 0.0f;

  for (int kc = 0; kc < Nn; kc += 32) {
    const int krow = kc + ql;
    const float4 ka = *(const float4*)&Bk[krow * Dd + hi * 8];
    const float4 kb = *(const float4*)&Bk[krow * Dd + hi * 8 + 4];
    float ke[8] = {ka.x, ka.y, ka.z, ka.w, kb.x, kb.y, kb.z, kb.w};
    bf16x8 kh, kl;
    split_frag(ke, kh, kl);

    // V fragments (B-operand): lane(ql,hi) holds V[kc+ks*16+hi*8+j][ql&15]
    bf16x8 vb[2];
    #pragma unroll
    for (int ks = 0; ks < 2; ++ks) {
      float e[8];
      #pragma unroll
      for (int j = 0; j < 8; ++j)
        e[j] = Vv[(kc + ks * 16 + hi * 8 + j) * Dd + d15];
      vb[ks] = cvt_frag(e);
    }

    #pragma unroll
    for (int qt = 0; qt < 2; ++qt) {
      f32x16 S;
      #pragma unroll
      for (int r = 0; r < 16; ++r) S[r] = 0.0f;
      S = __builtin_amdgcn_mfma_f32_32x32x16_bf16(kh, qh[qt],  S, 0, 0, 0);
      S = __builtin_amdgcn_mfma_f32_32x32x16_bf16(kh, qlo[qt], S, 0, 0, 0);
      S = __builtin_amdgcn_mfma_f32_32x32x16_bf16(kl, qh[qt],  S, 0, 0, 0);
      S = __builtin_amdgcn_mfma_f32_32x32x16_bf16(kl, qlo[qt], S, 0, 0, 0);

      float p[16];
      float ls = 0.0f;
      #pragma unroll
      for (int r = 0; r < 16; ++r) {
        float arg = S[r] - m_[qt];
        if (ty == 1) arg = fminf(arg, 0.0f);  // insurance; recompute is bitwise-identical
        p[r] = exp2f(arg);
        ls += p[r];
      }
      l_[qt] += ls;

      // repack P (rows k, col q=ql) into PV A-fragment (row q=ql, k along j)
      FragU pa0, pa1;
      {
        const unsigned wa = pk_bf16(p[0],  p[1]);
        const unsigned wb = pk_bf16(p[2],  p[3]);
        const unsigned wc = pk_bf16(p[4],  p[5]);
        const unsigned wd = pk_bf16(p[6],  p[7]);
        const unsigned swa = __shfl_xor(wa, 32);
        const unsigned swb = __shfl_xor(wb, 32);
        const unsigned swc = __shfl_xor(wc, 32);
        const unsigned swd = __shfl_xor(wd, 32);
        pa0.u[0] = hi ? swc : wa;   // j0,1
        pa0.u[1] = hi ? swd : wb;   // j2,3
        pa0.u[2] = hi ? wc  : swa;  // j4,5
        pa0.u[3] = hi ? wd  : swb;  // j6,7
        const unsigned we = pk_bf16(p[8],  p[9]);
        const unsigned wf = pk_bf16(p[10], p[11]);
        const unsigned wg = pk_bf16(p[12], p[13]);
        const unsigned wh = pk_bf16(p[14], p[15]);
        const unsigned swe = __shfl_xor(we, 32);
        const unsigned swf = __shfl_xor(wf, 32);
        const unsigned swg = __shfl_xor(wg, 32);
        const unsigned swh = __shfl_xor(wh, 32);
        pa1.u[0] = hi ? swg : we;
        pa1.u[1] = hi ? swh : wf;
        pa1.u[2] = hi ? wg  : swe;
        pa1.u[3] = hi ? wh  : swf;
      }
      o[qt] = __builtin_amdgcn_mfma_f32_32x32x16_bf16(pa0.v, vb[0], o[qt], 0, 0, 0);
      o[qt] = __builtin_amdgcn_mfma_f32_32x32x16_bf16(pa1.v, vb[1], o[qt], 0, 0, 0);
    }
  }

  // epilogue: merge l across half-waves, normalize, store
  const int b = slice / (Hh * Tt);
  const int h = (slice / Tt) % Hh;
  const int t = slice % Tt;
  float* __restrict__ outp = ctx + (size_t)ty * PROJ;
  #pragma unroll
  for (int qt = 0; qt < 2; ++qt) {
    const float lsum = l_[qt] + __shfl_xor(l_[qt], 32);
    const float linv = 1.0f / lsum;
    #pragma unroll
    for (int r = 0; r < 16; ++r) {
      const int qloc = (r & 3) + 8 * (r >> 2) + 4 * hi;
      const float lr = __shfl(linv, qloc);
      if (ql < 16) {
        const int n = q0 + qt * 32 + qloc;
        outp[(((size_t)b * Nn + n) * Tt + t) * Ee + h * Dd + ql] = o[qt][r] * lr;
      }
    }
  }
}

// ---------------------------------------------------------------------------
// Kernel O (known-good): out[ty] = ctx[ty] @ Wout + bout
// ---------------------------------------------------------------------------
__global__ __launch_bounds__(256) void out_kernel(
    const float* __restrict__ ctx, const float* __restrict__ Wout,
    const float* __restrict__ bout, float* __restrict__ out)
{
  __shared__ float Ws[Ee * Ee];
  __shared__ float Xs[MT * Ee];
  const int ty  = blockIdx.y;
  const int tid = threadIdx.x;
  const float* __restrict__ x = ctx + (size_t)ty * PROJ;
  const int tk0 = blockIdx.x * MT;

  for (int i = tid * 4; i < Ee * Ee; i += 1024)
    *(float4*)&Ws[i] = *(const float4*)&Wout[i];
  for (int i = tid * 4; i < MT * Ee; i += 1024)
    *(float4*)&Xs[i] = *(const float4*)&x[(size_t)tk0 * Ee + i];
  __syncthreads();

  const int c4 = (tid & 31) * 4;
  const int tg = tid >> 5;

  float4 acc[4];
  #pragma unroll
  for (int i = 0; i < 4; ++i) acc[i] = make_float4(0.f, 0.f, 0.f, 0.f);

  for (int k = 0; k < Ee; k += 4) {
    float4 w0 = *(const float4*)&Ws[(k + 0) * Ee + c4];
    float4 w1 = *(const float4*)&Ws[(k + 1) * Ee + c4];
    float4 w2 = *(const float4*)&Ws[(k + 2) * Ee + c4];
    float4 w3 = *(const float4*)&Ws[(k + 3) * Ee + c4];
    #pragma unroll
    for (int tt = 0; tt < 4; ++tt) {
      float4 xv = *(const float4*)&Xs[(tg * 4 + tt) * Ee + k];
      fma4(acc[tt], xv.x, w0); fma4(acc[tt], xv.y, w1);
      fma4(acc[tt], xv.z, w2); fma4(acc[tt], xv.w, w3);
    }
  }

  const float4 bv = *(const float4*)&bout[c4];
  #pragma unroll
  for (int tt = 0; tt < 4; ++tt) {
    const int tk = tk0 + tg * 4 + tt;
    float4 r = acc[tt];
    r.x += bv.x; r.y += bv.y; r.z += bv.z; r.w += bv.w;
    *(float4*)&out[(size_t)ty * PROJ + (size_t)tk * Ee + c4] = r;
  }
}

// ---------------------------------------------------------------------------
extern "C" void kernel_launch(void* const* d_in, const int* in_sizes, int n_in,
                              void* d_out, int out_size, void* d_ws, size_t ws_size,
                              hipStream_t stream) {
  const float* fq  = (const float*)d_in[0];
  const float* fk  = (const float*)d_in[1];
  const float* fv  = (const float*)d_in[2];
  const float* sq  = (const float*)d_in[3];
  const float* sk  = (const float*)d_in[4];
  const float* sv  = (const float*)d_in[5];
  const float* WfQ = (const float*)d_in[6];
  const float* WfK = (const float*)d_in[7];
  const float* WfV = (const float*)d_in[8];
  const float* WsQ = (const float*)d_in[9];
  const float* WsK = (const float*)d_in[10];
  const float* WsV = (const float*)d_in[11];
  const float* Kj  = (const float*)d_in[12];
  const float* Vfp = (const float*)d_in[13];
  const float* Wout = (const float*)d_in[14];
  const float* bout = (const float*)d_in[15];

  float* proj = (float*)d_ws;                  // 7 * PROJ floats
  float* ctx  = proj + (size_t)7 * PROJ;       // 4 * PROJ floats

  PtrPack pp;
  pp.x[0] = fq; pp.x[1] = fk; pp.x[2] = fv;
  pp.x[3] = sq; pp.x[4] = sk; pp.x[5] = sv;
  pp.W[0] = WfQ; pp.W[1] = WfK; pp.W[2] = WfV;
  pp.W[3] = WsQ; pp.W[4] = WsK; pp.W[5] = WsV;

  proj_kernel<<<dim3(NTOK / MT, 6), 256, 0, stream>>>(pp, Kj, Vfp, proj);
  attn_mfma_kernel<<<dim3(SLICES, 4), 512, 0, stream>>>(proj, ctx);
  out_kernel<<<dim3(NTOK / MT, 4), 256, 0, stream>>>(ctx, Wout, bout, (float*)d_out);
}

// Round 5
// 264.346 us; speedup vs baseline: 1.6941x; 1.0425x over previous
//
#include <hip/hip_runtime.h>
#include <math.h>

// Dims (fixed by the problem)
constexpr int Bb = 2, Nn = 512, Tt = 12, Ee = 128, Hh = 8, Dd = 16;
constexpr int NTOK   = Bb * Nn * Tt;      // 12288 tokens
constexpr int PROJ   = NTOK * Ee;         // 1572864 floats per [B,N,T,E] tensor
constexpr int SLICES = Bb * Hh * Tt;      // 192 attention slices
constexpr int NSL    = Nn * Dd;           // 8192 elems per (slice, tensor)
constexpr int SLE    = SLICES * NSL;      // 1572864 elems per tensor

// Workspace layout:
//   qk  : 5 QK-role tensors x {hi,lo} bf16, head-major [s][hl][slice][n][d]
//         compact s: 0=Qf 1=Kf 2=Qs 3=Ks 4=Qfs            (10 * 3MB)
//   vt  : 2 V tensors bf16 TRANSPOSED [s][slice][d][n]     (2 * 3MB)
//   wf  : 7 weight mats x {hi,lo} in B-fragment layout     (0.46MB)
//   ctx : 4 attention outputs fp32 token-major [B,N,T,E]   (4 * 6MB)

struct PtrPack { const float* x[6]; const float* W[6]; };
struct WPack   { const float* W[7]; };

typedef __attribute__((ext_vector_type(8)))  short bf16x8;
typedef __attribute__((ext_vector_type(16))) float f32x16;
union FragU { bf16x8 v; unsigned u[4]; };

__device__ __forceinline__ unsigned pk_bf16(float a, float b) {
  unsigned r;
  asm("v_cvt_pk_bf16_f32 %0, %1, %2" : "=v"(r) : "v"(a), "v"(b));
  return r;
}
__device__ __forceinline__ unsigned short bf16_1(float a) {
  return (unsigned short)(pk_bf16(a, a) & 0xffffu);
}
// fp32 -> bf16 hi + bf16 residual-lo fragments (8 elems)
__device__ __forceinline__ void split_frag(const float e[8], bf16x8& hv, bf16x8& lv) {
  FragU H, L;
  #pragma unroll
  for (int i = 0; i < 4; ++i) {
    const unsigned h = pk_bf16(e[2*i], e[2*i+1]);
    const float h0 = __uint_as_float(h << 16);
    const float h1 = __uint_as_float(h & 0xffff0000u);
    L.u[i] = pk_bf16(e[2*i] - h0, e[2*i+1] - h1);
    H.u[i] = h;
  }
  hv = H.v; lv = L.v;
}

// ---------------------------------------------------------------------------
// prep_w: split 7 weight matrices into hi/lo bf16 B-operand fragments.
// Fragment slot e = ct*512 + ks*64 + lane; lane(ql,hi) holds
// W[ks*16 + hi*8 + j][ct*32 + ql], j=0..7.  Linear: (m*2+hl)*2048*8 + e*8.
// ---------------------------------------------------------------------------
__global__ __launch_bounds__(256) void prep_w_kernel(
    WPack wp, unsigned short* __restrict__ wf)
{
  const int m = blockIdx.x;
  const float* __restrict__ W = wp.W[m];
  for (int e = threadIdx.x; e < 2048; e += 256) {
    const int ct = e >> 9, ks = (e >> 6) & 7, lane = e & 63;
    const int ql = lane & 31, hi = lane >> 5;
    const int c = ct * 32 + ql, k0 = ks * 16 + hi * 8;
    float w[8];
    #pragma unroll
    for (int j = 0; j < 8; ++j) w[j] = W[(size_t)(k0 + j) * Ee + c];
    bf16x8 hv, lv;
    split_frag(w, hv, lv);
    *(bf16x8*)&wf[((size_t)(m * 2 + 0) * 2048 + e) * 8] = hv;
    *(bf16x8*)&wf[((size_t)(m * 2 + 1) * 2048 + e) * 8] = lv;
  }
}

// ---------------------------------------------------------------------------
// proj_mfma: y = x @ W via 32x32x16 bf16 MFMA, 3-term hi/lo split
// (4-term for ty==3: Qfs amplifies Qs error by 1/(Vfp+1e-5)).
// Block = 256 thr = 4 waves; wave ct owns cols [ct*32, ct*32+32); block owns
// 32 tokens.  A-frag: lane(ql,hi) = x[tok0+ql][ks*16+hi*8+j] (validated
// layout from attn round 4).  Epilogue writes attn-ready operands.
// ---------------------------------------------------------------------------
__global__ __launch_bounds__(256) void proj_mfma_kernel(
    PtrPack pp, const float* __restrict__ Kj, const float* __restrict__ Vfp,
    unsigned short* __restrict__ qk, unsigned short* __restrict__ vt,
    const unsigned short* __restrict__ wf)
{
  const int ty   = blockIdx.y;
  const int tok0 = blockIdx.x * 32;
  const int wave = threadIdx.x >> 6;
  const int lane = threadIdx.x & 63;
  const int ql = lane & 31, hi = lane >> 5;

  f32x16 acc;
  #pragma unroll
  for (int r = 0; r < 16; ++r) acc[r] = 0.f;

  const float* __restrict__ xrow = pp.x[ty] + (size_t)(tok0 + ql) * Ee;
  const unsigned short* __restrict__ wbase =
      wf + ((size_t)(ty * 2) * 2048 + wave * 512 + lane) * 8;

  for (int ks = 0; ks < 8; ++ks) {
    const float4 a0 = *(const float4*)&xrow[ks * 16 + hi * 8];
    const float4 a1 = *(const float4*)&xrow[ks * 16 + hi * 8 + 4];
    float e8[8] = {a0.x, a0.y, a0.z, a0.w, a1.x, a1.y, a1.z, a1.w};
    bf16x8 xh, xl;
    split_frag(e8, xh, xl);
    const bf16x8 wh = *(const bf16x8*)&wbase[(size_t)ks * 512];
    const bf16x8 wl = *(const bf16x8*)&wbase[(size_t)ks * 512 + 2048 * 8];
    acc = __builtin_amdgcn_mfma_f32_32x32x16_bf16(xh, wh, acc, 0, 0, 0);
    acc = __builtin_amdgcn_mfma_f32_32x32x16_bf16(xh, wl, acc, 0, 0, 0);
    acc = __builtin_amdgcn_mfma_f32_32x32x16_bf16(xl, wh, acc, 0, 0, 0);
    if (ty == 3)
      acc = __builtin_amdgcn_mfma_f32_32x32x16_bf16(xl, wl, acc, 0, 0, 0);
  }

  const int c = wave * 32 + ql;     // global col 0..127
  const int h = c >> 4, d = c & 15;
  #pragma unroll
  for (int r = 0; r < 16; ++r) {
    const int tok = tok0 + (r & 3) + 8 * (r >> 2) + 4 * hi;
    const int t = tok % Tt;
    const int n = (tok / Tt) % Nn;
    const int b = tok / (Nn * Tt);
    const int slice = (b * Hh + h) * Tt + t;
    const size_t off = (size_t)slice * NSL + n * 16 + d;
    const float v = acc[r];
    if (ty == 2 || ty == 5) {
      const int vs = (ty == 5);
      vt[(size_t)vs * SLE + (size_t)slice * NSL + d * 512 + n] = bf16_1(v);
    } else {
      const int s = (ty == 0) ? 0 : (ty == 1) ? 1 : (ty == 3) ? 2 : 3;
      const unsigned short vh = bf16_1(v);
      qk[(size_t)(s * 2 + 0) * SLE + off] = vh;
      qk[(size_t)(s * 2 + 1) * SLE + off] =
          bf16_1(v - __uint_as_float((unsigned)vh << 16));
      if (ty == 3) {  // FlowSpeed nonlinearity from fp32 acc -> Qfs (slot 4)
        const float kj = Kj[n];
        const float iv = 1.0f / (Vfp[n] + 1e-5f);
        const float g  = kj * (v - v * v * iv);
        const unsigned short gh = bf16_1(g);
        qk[(size_t)(4 * 2 + 0) * SLE + off] = gh;
        qk[(size_t)(4 * 2 + 1) * SLE + off] =
            bf16_1(g - __uint_as_float((unsigned)gh << 16));
      }
    }
  }
}

// ---------------------------------------------------------------------------
// attn: MFMA flash attention (round-4-validated structure), now consuming
// pre-split bf16 operands.  Block = 512 thr = one (slice,type); wave owns 64
// q-rows.  QK^T swapped (A=keys, B=queries): S[r] = s[k(r,hi), q=ql],
// k(r,hi) = (r&3)+8*(r>>2)+4*hi.  3-term split for ff/sf/ss; 4-term + exact
// max pre-pass (bitwise-identical recompute) for fs.  Scale*log2e applied at
// the exp2 argument (operands stored unscaled).
// ---------------------------------------------------------------------------
__global__ __launch_bounds__(512) void attn_mfma_kernel(
    const unsigned short* __restrict__ qk, const unsigned short* __restrict__ vt,
    float* __restrict__ ctx)
{
  const int slice = blockIdx.x;
  const int ty    = blockIdx.y;
  // compact-slot maps (proj slots {0,1,3,4,6} -> {0,1,2,3,4}):
  const int a_s[4] = {0, 1, 3, 2};   // queries: Qf, Kf, Ks, Qs
  const int b_s[4] = {1, 4, 0, 3};   // keys   : Kf, Qfs, Qf, Ks
  const int v_s[4] = {0, 0, 1, 1};   // values : Vf, Vf, Vs, Vs

  const unsigned short* __restrict__ Ah =
      qk + (size_t)(a_s[ty] * 2 + 0) * SLE + (size_t)slice * NSL;
  const unsigned short* __restrict__ Al =
      qk + (size_t)(a_s[ty] * 2 + 1) * SLE + (size_t)slice * NSL;
  const unsigned short* __restrict__ Kh_ =
      qk + (size_t)(b_s[ty] * 2 + 0) * SLE + (size_t)slice * NSL;
  const unsigned short* __restrict__ Kl_ =
      qk + (size_t)(b_s[ty] * 2 + 1) * SLE + (size_t)slice * NSL;
  const unsigned short* __restrict__ Vt_ =
      vt + (size_t)v_s[ty] * SLE + (size_t)slice * NSL;

  const int tid  = threadIdx.x;
  const int wave = tid >> 6;
  const int lane = tid & 63;
  const int hi   = lane >> 5;
  const int ql   = lane & 31;
  const int q0   = wave * 64;
  const int d15  = ql & 15;

  const float SC = 0.25f * 1.4426950408889634f;  // 1/sqrt(D) * log2(e)

  // Q fragments (B-operand): lane(ql,hi) holds Q[q0+qt*32+ql][hi*8+j]
  bf16x8 qh[2], qlo[2];
  #pragma unroll
  for (int qt = 0; qt < 2; ++qt) {
    const int qrow = q0 + qt * 32 + ql;
    qh[qt]  = *(const bf16x8*)&Ah[qrow * 16 + hi * 8];
    qlo[qt] = *(const bf16x8*)&Al[qrow * 16 + hi * 8];
  }

  // -------- pass 1 (fs only): exact row max of the pass-2 S values --------
  float msc[2] = {0.0f, 0.0f};
  if (ty == 1) {
    float mx[2] = {-1e30f, -1e30f};
    for (int kc = 0; kc < Nn; kc += 32) {
      const int krow = kc + ql;
      const bf16x8 kh = *(const bf16x8*)&Kh_[krow * 16 + hi * 8];
      const bf16x8 kl = *(const bf16x8*)&Kl_[krow * 16 + hi * 8];
      #pragma unroll
      for (int qt = 0; qt < 2; ++qt) {
        f32x16 S;
        #pragma unroll
        for (int r = 0; r < 16; ++r) S[r] = 0.0f;
        S = __builtin_amdgcn_mfma_f32_32x32x16_bf16(kh, qh[qt],  S, 0, 0, 0);
        S = __builtin_amdgcn_mfma_f32_32x32x16_bf16(kh, qlo[qt], S, 0, 0, 0);
        S = __builtin_amdgcn_mfma_f32_32x32x16_bf16(kl, qh[qt],  S, 0, 0, 0);
        S = __builtin_amdgcn_mfma_f32_32x32x16_bf16(kl, qlo[qt], S, 0, 0, 0);
        #pragma unroll
        for (int r = 0; r < 16; ++r) mx[qt] = fmaxf(mx[qt], S[r]);
      }
    }
    #pragma unroll
    for (int qt = 0; qt < 2; ++qt)
      msc[qt] = fmaxf(mx[qt], __shfl_xor(mx[qt], 32)) * SC;
  }

  // -------- pass 2: softmax-weighted PV --------
  f32x16 o[2];
  float  l_[2] = {0.0f, 0.0f};
  #pragma unroll
  for (int qt = 0; qt < 2; ++qt)
    #pragma unroll
    for (int r = 0; r < 16; ++r) o[qt][r] = 0.0f;

  for (int kc = 0; kc < Nn; kc += 32) {
    const int krow = kc + ql;
    const bf16x8 kh = *(const bf16x8*)&Kh_[krow * 16 + hi * 8];
    const bf16x8 kl = *(const bf16x8*)&Kl_[krow * 16 + hi * 8];
    // V fragments (B-operand): lane(ql,hi) holds V[kc+ks*16+hi*8+j][d15]
    const bf16x8 vb0 = *(const bf16x8*)&Vt_[d15 * 512 + kc + hi * 8];
    const bf16x8 vb1 = *(const bf16x8*)&Vt_[d15 * 512 + kc + 16 + hi * 8];

    #pragma unroll
    for (int qt = 0; qt < 2; ++qt) {
      f32x16 S;
      #pragma unroll
      for (int r = 0; r < 16; ++r) S[r] = 0.0f;
      S = __builtin_amdgcn_mfma_f32_32x32x16_bf16(kh, qh[qt],  S, 0, 0, 0);
      S = __builtin_amdgcn_mfma_f32_32x32x16_bf16(kh, qlo[qt], S, 0, 0, 0);
      S = __builtin_amdgcn_mfma_f32_32x32x16_bf16(kl, qh[qt],  S, 0, 0, 0);
      if (ty == 1)
        S = __builtin_amdgcn_mfma_f32_32x32x16_bf16(kl, qlo[qt], S, 0, 0, 0);

      float p[16];
      float ls = 0.0f;
      #pragma unroll
      for (int r = 0; r < 16; ++r) {
        float arg = fmaf(S[r], SC, -msc[qt]);
        if (ty == 1) arg = fminf(arg, 0.0f);  // insurance; recompute identical
        p[r] = exp2f(arg);
        ls += p[r];
      }
      l_[qt] += ls;

      // repack P (rows k, col q=ql) into PV A-fragment (row q=ql, k along j)
      FragU pa0, pa1;
      {
        const unsigned wa = pk_bf16(p[0],  p[1]);
        const unsigned wb = pk_bf16(p[2],  p[3]);
        const unsigned wc = pk_bf16(p[4],  p[5]);
        const unsigned wd = pk_bf16(p[6],  p[7]);
        const unsigned swa = __shfl_xor(wa, 32);
        const unsigned swb = __shfl_xor(wb, 32);
        const unsigned swc = __shfl_xor(wc, 32);
        const unsigned swd = __shfl_xor(wd, 32);
        pa0.u[0] = hi ? swc : wa;
        pa0.u[1] = hi ? swd : wb;
        pa0.u[2] = hi ? wc  : swa;
        pa0.u[3] = hi ? wd  : swb;
        const unsigned we = pk_bf16(p[8],  p[9]);
        const unsigned wf_ = pk_bf16(p[10], p[11]);
        const unsigned wg = pk_bf16(p[12], p[13]);
        const unsigned wh = pk_bf16(p[14], p[15]);
        const unsigned swe = __shfl_xor(we, 32);
        const unsigned swf = __shfl_xor(wf_, 32);
        const unsigned swg = __shfl_xor(wg, 32);
        const unsigned swh = __shfl_xor(wh, 32);
        pa1.u[0] = hi ? swg : we;
        pa1.u[1] = hi ? swh : wf_;
        pa1.u[2] = hi ? wg  : swe;
        pa1.u[3] = hi ? wh  : swf;
      }
      o[qt] = __builtin_amdgcn_mfma_f32_32x32x16_bf16(pa0.v, vb0, o[qt], 0, 0, 0);
      o[qt] = __builtin_amdgcn_mfma_f32_32x32x16_bf16(pa1.v, vb1, o[qt], 0, 0, 0);
    }
  }

  // epilogue: merge l across half-waves, normalize, store (validated)
  const int b = slice / (Hh * Tt);
  const int h = (slice / Tt) % Hh;
  const int t = slice % Tt;
  float* __restrict__ outp = ctx + (size_t)ty * PROJ;
  #pragma unroll
  for (int qt = 0; qt < 2; ++qt) {
    const float lsum = l_[qt] + __shfl_xor(l_[qt], 32);
    const float linv = 1.0f / lsum;
    #pragma unroll
    for (int r = 0; r < 16; ++r) {
      const int qloc = (r & 3) + 8 * (r >> 2) + 4 * hi;
      const float lr = __shfl(linv, qloc);
      if (ql < 16) {
        const int n = q0 + qt * 32 + qloc;
        outp[(((size_t)b * Nn + n) * Tt + t) * Ee + h * Dd + ql] = o[qt][r] * lr;
      }
    }
  }
}

// ---------------------------------------------------------------------------
// out_mfma: out[ty] = ctx[ty] @ Wout + bout  (MFMA, 3-term inline split)
// ---------------------------------------------------------------------------
__global__ __launch_bounds__(256) void out_mfma_kernel(
    const float* __restrict__ ctx, const unsigned short* __restrict__ wf,
    const float* __restrict__ bout, float* __restrict__ out)
{
  const int ty   = blockIdx.y;
  const int tok0 = blockIdx.x * 32;
  const int wave = threadIdx.x >> 6;
  const int lane = threadIdx.x & 63;
  const int ql = lane & 31, hi = lane >> 5;

  f32x16 acc;
  #pragma unroll
  for (int r = 0; r < 16; ++r) acc[r] = 0.f;

  const float* __restrict__ xrow =
      ctx + (size_t)ty * PROJ + (size_t)(tok0 + ql) * Ee;
  const unsigned short* __restrict__ wbase =
      wf + ((size_t)(6 * 2) * 2048 + wave * 512 + lane) * 8;

  for (int ks = 0; ks < 8; ++ks) {
    const float4 a0 = *(const float4*)&xrow[ks * 16 + hi * 8];
    const float4 a1 = *(const float4*)&xrow[ks * 16 + hi * 8 + 4];
    float e8[8] = {a0.x, a0.y, a0.z, a0.w, a1.x, a1.y, a1.z, a1.w};
    bf16x8 xh, xl;
    split_frag(e8, xh, xl);
    const bf16x8 wh = *(const bf16x8*)&wbase[(size_t)ks * 512];
    const bf16x8 wl = *(const bf16x8*)&wbase[(size_t)ks * 512 + 2048 * 8];
    acc = __builtin_amdgcn_mfma_f32_32x32x16_bf16(xh, wh, acc, 0, 0, 0);
    acc = __builtin_amdgcn_mfma_f32_32x32x16_bf16(xh, wl, acc, 0, 0, 0);
    acc = __builtin_amdgcn_mfma_f32_32x32x16_bf16(xl, wh, acc, 0, 0, 0);
  }

  const int c = wave * 32 + ql;
  const float bc = bout[c];
  #pragma unroll
  for (int r = 0; r < 16; ++r) {
    const int tok = tok0 + (r & 3) + 8 * (r >> 2) + 4 * hi;
    out[(size_t)ty * PROJ + (size_t)tok * Ee + c] = acc[r] + bc;
  }
}

// ---------------------------------------------------------------------------
extern "C" void kernel_launch(void* const* d_in, const int* in_sizes, int n_in,
                              void* d_out, int out_size, void* d_ws, size_t ws_size,
                              hipStream_t stream) {
  const float* fq  = (const float*)d_in[0];
  const float* fk  = (const float*)d_in[1];
  const float* fv  = (const float*)d_in[2];
  const float* sq  = (const float*)d_in[3];
  const float* sk  = (const float*)d_in[4];
  const float* sv  = (const float*)d_in[5];
  const float* WfQ = (const float*)d_in[6];
  const float* WfK = (const float*)d_in[7];
  const float* WfV = (const float*)d_in[8];
  const float* WsQ = (const float*)d_in[9];
  const float* WsK = (const float*)d_in[10];
  const float* WsV = (const float*)d_in[11];
  const float* Kj  = (const float*)d_in[12];
  const float* Vfp = (const float*)d_in[13];
  const float* Wout = (const float*)d_in[14];
  const float* bout = (const float*)d_in[15];

  unsigned short* qk = (unsigned short*)d_ws;          // 10 * SLE ushorts
  unsigned short* vt = qk + (size_t)10 * SLE;          // 2 * SLE ushorts
  unsigned short* wf = vt + (size_t)2 * SLE;           // 7*2*2048*8 = 229376
  float* ctx = (float*)(wf + 229376);                  // 4 * PROJ floats

  PtrPack pp;
  pp.x[0] = fq; pp.x[1] = fk; pp.x[2] = fv;
  pp.x[3] = sq; pp.x[4] = sk; pp.x[5] = sv;
  pp.W[0] = WfQ; pp.W[1] = WfK; pp.W[2] = WfV;
  pp.W[3] = WsQ; pp.W[4] = WsK; pp.W[5] = WsV;
  WPack wp;
  wp.W[0] = WfQ; wp.W[1] = WfK; wp.W[2] = WfV;
  wp.W[3] = WsQ; wp.W[4] = WsK; wp.W[5] = WsV; wp.W[6] = Wout;

  prep_w_kernel<<<7, 256, 0, stream>>>(wp, wf);
  proj_mfma_kernel<<<dim3(NTOK / 32, 6), 256, 0, stream>>>(pp, Kj, Vfp, qk, vt, wf);
  attn_mfma_kernel<<<dim3(SLICES, 4), 512, 0, stream>>>(qk, vt, ctx);
  out_mfma_kernel<<<dim3(NTOK / 32, 4), 256, 0, stream>>>(ctx, wf, bout, (float*)d_out);
}

// Round 6
// 228.963 us; speedup vs baseline: 1.9559x; 1.1545x over previous
//
#include <hip/hip_runtime.h>
#include <math.h>

// Dims (fixed by the problem)
constexpr int Bb = 2, Nn = 512, Tt = 12, Ee = 128, Hh = 8, Dd = 16;
constexpr int NTOK   = Bb * Nn * Tt;      // 12288 tokens
constexpr int PROJ   = NTOK * Ee;         // 1572864 floats per [B,N,T,E] tensor
constexpr int SLICES = Bb * Hh * Tt;      // 192 attention slices
constexpr int NSL    = Nn * Dd;           // 8192 elems per (slice, tensor)
constexpr int SLE    = SLICES * NSL;      // 1572864 elems per tensor

// Workspace layout:
//   qk  : 5 QK-role tensors x {hi,lo} bf16, head-major [s][hl][slice][n][d]
//         compact s: 0=Qf 1=Kf 2=Qs 3=Ks 4=Qfs            (10 * 3MB)
//   vt  : 2 V tensors bf16 TRANSPOSED [s][slice][d][n]     (2 * 3MB)
//   wf  : 7 weight mats x {hi,lo} in B-fragment layout     (0.46MB)
//   ctx : 4 attention outputs fp32 token-major [B,N,T,E]   (4 * 6MB)

struct PtrPack { const float* x[6]; const float* W[6]; };
struct WPack   { const float* W[7]; };

typedef __attribute__((ext_vector_type(8)))  short bf16x8;
typedef __attribute__((ext_vector_type(16))) float f32x16;
union FragU { bf16x8 v; unsigned u[4]; };

__device__ __forceinline__ unsigned pk_bf16(float a, float b) {
  unsigned r;
  asm("v_cvt_pk_bf16_f32 %0, %1, %2" : "=v"(r) : "v"(a), "v"(b));
  return r;
}
__device__ __forceinline__ unsigned short bf16_1(float a) {
  return (unsigned short)(pk_bf16(a, a) & 0xffffu);
}
// fp32 -> bf16 hi + bf16 residual-lo fragments (8 elems)
__device__ __forceinline__ void split_frag(const float e[8], bf16x8& hv, bf16x8& lv) {
  FragU H, L;
  #pragma unroll
  for (int i = 0; i < 4; ++i) {
    const unsigned h = pk_bf16(e[2*i], e[2*i+1]);
    const float h0 = __uint_as_float(h << 16);
    const float h1 = __uint_as_float(h & 0xffff0000u);
    L.u[i] = pk_bf16(e[2*i] - h0, e[2*i+1] - h1);
    H.u[i] = h;
  }
  hv = H.v; lv = L.v;
}

// ---------------------------------------------------------------------------
// prep_w: split 7 weight matrices into hi/lo bf16 B-operand fragments.
// Fragment slot e = ct*512 + ks*64 + lane; lane(ql,hi) holds
// W[ks*16 + hi*8 + j][ct*32 + ql], j=0..7.  Linear: (m*2+hl)*2048*8 + e*8.
// ---------------------------------------------------------------------------
__global__ __launch_bounds__(256) void prep_w_kernel(
    WPack wp, unsigned short* __restrict__ wf)
{
  const int m = blockIdx.x;
  const float* __restrict__ W = wp.W[m];
  for (int e = threadIdx.x; e < 2048; e += 256) {
    const int ct = e >> 9, ks = (e >> 6) & 7, lane = e & 63;
    const int ql = lane & 31, hi = lane >> 5;
    const int c = ct * 32 + ql, k0 = ks * 16 + hi * 8;
    float w[8];
    #pragma unroll
    for (int j = 0; j < 8; ++j) w[j] = W[(size_t)(k0 + j) * Ee + c];
    bf16x8 hv, lv;
    split_frag(w, hv, lv);
    *(bf16x8*)&wf[((size_t)(m * 2 + 0) * 2048 + e) * 8] = hv;
    *(bf16x8*)&wf[((size_t)(m * 2 + 1) * 2048 + e) * 8] = lv;
  }
}

// ---------------------------------------------------------------------------
// proj_mfma: y = x @ W via 32x32x16 bf16 MFMA, 3-term hi/lo split (4-term
// for ty==3).  Block = (b, t, n-chunk of 32): all 32 output rows share t, so
// per h the outputs form contiguous [slice][n0..n0+31][16] runs.  Results
// staged in LDS (fp32, pad 132), then written out coalesced:
//   qk: thread=(h,n) -> 32B-contiguous bf16x8 stores per plane
//   vt: thread=(h,d) -> 64B n-run per d
// ---------------------------------------------------------------------------
__global__ __launch_bounds__(256) void proj_mfma_kernel(
    PtrPack pp, const float* __restrict__ Kj, const float* __restrict__ Vfp,
    unsigned short* __restrict__ qk, unsigned short* __restrict__ vt,
    const unsigned short* __restrict__ wf)
{
  __shared__ float XS[32][132];
  const int ty = blockIdx.y;
  const int g  = blockIdx.x;          // (bt<<4) | nc
  const int nc = g & 15;
  const int bt = g >> 4;              // 0..23
  const int b  = bt / Tt, t = bt % Tt;
  const int n0 = nc * 32;
  const int wave = threadIdx.x >> 6, lane = threadIdx.x & 63;
  const int ql = lane & 31, hi = lane >> 5;

  f32x16 acc;
  #pragma unroll
  for (int r = 0; r < 16; ++r) acc[r] = 0.f;

  const float* __restrict__ xrow =
      pp.x[ty] + ((size_t)(b * Nn + n0 + ql) * Tt + t) * Ee;
  const unsigned short* __restrict__ wbase =
      wf + ((size_t)(ty * 2) * 2048 + wave * 512 + lane) * 8;

  for (int ks = 0; ks < 8; ++ks) {
    const float4 a0 = *(const float4*)&xrow[ks * 16 + hi * 8];
    const float4 a1 = *(const float4*)&xrow[ks * 16 + hi * 8 + 4];
    float e8[8] = {a0.x, a0.y, a0.z, a0.w, a1.x, a1.y, a1.z, a1.w};
    bf16x8 xh, xl;
    split_frag(e8, xh, xl);
    const bf16x8 wh = *(const bf16x8*)&wbase[(size_t)ks * 512];
    const bf16x8 wl = *(const bf16x8*)&wbase[(size_t)ks * 512 + 2048 * 8];
    acc = __builtin_amdgcn_mfma_f32_32x32x16_bf16(xh, wh, acc, 0, 0, 0);
    acc = __builtin_amdgcn_mfma_f32_32x32x16_bf16(xh, wl, acc, 0, 0, 0);
    acc = __builtin_amdgcn_mfma_f32_32x32x16_bf16(xl, wh, acc, 0, 0, 0);
    if (ty == 3)
      acc = __builtin_amdgcn_mfma_f32_32x32x16_bf16(xl, wl, acc, 0, 0, 0);
  }

  // stage C tile: row = n-offset qloc(r,hi), col = wave*32+ql
  #pragma unroll
  for (int r = 0; r < 16; ++r)
    XS[(r & 3) + 8 * (r >> 2) + 4 * hi][wave * 32 + ql] = acc[r];
  __syncthreads();

  if (ty == 2 || ty == 5) {           // V tensors -> transposed [slice][d][n]
    if (threadIdx.x < 128) {
      const int h = threadIdx.x >> 4, d = threadIdx.x & 15;
      const int slice = (b * Hh + h) * Tt + t;
      float v[32];
      #pragma unroll
      for (int n = 0; n < 32; ++n) v[n] = XS[n][h * 16 + d];
      FragU F[4];
      #pragma unroll
      for (int i = 0; i < 16; ++i)
        F[i >> 2].u[i & 3] = pk_bf16(v[2 * i], v[2 * i + 1]);
      unsigned short* __restrict__ dst =
          vt + (size_t)(ty == 5) * SLE + (size_t)slice * NSL + d * 512 + n0;
      #pragma unroll
      for (int i = 0; i < 4; ++i) *(bf16x8*)&dst[i * 8] = F[i].v;
    }
  } else {                            // QK-role tensors -> hi/lo planes
    const int h = threadIdx.x >> 5, nn = threadIdx.x & 31;
    const int slice = (b * Hh + h) * Tt + t;
    const int n = n0 + nn;
    float v[16];
    #pragma unroll
    for (int d = 0; d < 16; ++d) v[d] = XS[nn][h * 16 + d];
    FragU HI[2], LO[2];
    #pragma unroll
    for (int i = 0; i < 8; ++i) {
      const unsigned hw = pk_bf16(v[2 * i], v[2 * i + 1]);
      const float h0 = __uint_as_float(hw << 16);
      const float h1 = __uint_as_float(hw & 0xffff0000u);
      HI[i >> 2].u[i & 3] = hw;
      LO[i >> 2].u[i & 3] = pk_bf16(v[2 * i] - h0, v[2 * i + 1] - h1);
    }
    const int s = (ty == 0) ? 0 : (ty == 1) ? 1 : (ty == 3) ? 2 : 3;
    unsigned short* __restrict__ hp =
        qk + (size_t)(s * 2 + 0) * SLE + (size_t)slice * NSL + n * 16;
    unsigned short* __restrict__ lp =
        qk + (size_t)(s * 2 + 1) * SLE + (size_t)slice * NSL + n * 16;
    *(bf16x8*)&hp[0] = HI[0].v;  *(bf16x8*)&hp[8] = HI[1].v;
    *(bf16x8*)&lp[0] = LO[0].v;  *(bf16x8*)&lp[8] = LO[1].v;
    if (ty == 3) {                    // FlowSpeed nonlinearity -> Qfs (s=4)
      const float kj = Kj[n];
      const float iv = 1.0f / (Vfp[n] + 1e-5f);
      float gv[16];
      #pragma unroll
      for (int d = 0; d < 16; ++d) gv[d] = kj * (v[d] - v[d] * v[d] * iv);
      FragU GH[2], GL[2];
      #pragma unroll
      for (int i = 0; i < 8; ++i) {
        const unsigned hw = pk_bf16(gv[2 * i], gv[2 * i + 1]);
        const float h0 = __uint_as_float(hw << 16);
        const float h1 = __uint_as_float(hw & 0xffff0000u);
        GH[i >> 2].u[i & 3] = hw;
        GL[i >> 2].u[i & 3] = pk_bf16(gv[2 * i] - h0, gv[2 * i + 1] - h1);
      }
      unsigned short* __restrict__ gp =
          qk + (size_t)(4 * 2 + 0) * SLE + (size_t)slice * NSL + n * 16;
      unsigned short* __restrict__ glp =
          qk + (size_t)(4 * 2 + 1) * SLE + (size_t)slice * NSL + n * 16;
      *(bf16x8*)&gp[0]  = GH[0].v;  *(bf16x8*)&gp[8]  = GH[1].v;
      *(bf16x8*)&glp[0] = GL[0].v;  *(bf16x8*)&glp[8] = GL[1].v;
    }
  }
}

// ---------------------------------------------------------------------------
// attn: MFMA flash attention (validated structure).  Block = 512 thr = one
// (slice,type); wave owns 64 q-rows.  QK^T swapped: S[r] = s[k(r,hi), q=ql],
// k(r,hi) = (r&3)+8*(r>>2)+4*hi.  3-term split for ff/sf/ss (m=0 raw exp2);
// 4-term + deferred-rescale online max for fs (single pass: rescale o,l only
// when the tile max grows past m+8; arg <= 8 bounded -> no overflow).
// S zero-init via constant Z register as MFMA C-operand.
// ---------------------------------------------------------------------------
__global__ __launch_bounds__(512) void attn_mfma_kernel(
    const unsigned short* __restrict__ qk, const unsigned short* __restrict__ vt,
    float* __restrict__ ctx)
{
  const int slice = blockIdx.x;
  const int ty    = blockIdx.y;
  const int a_s[4] = {0, 1, 3, 2};   // queries: Qf, Kf, Ks, Qs
  const int b_s[4] = {1, 4, 0, 3};   // keys   : Kf, Qfs, Qf, Ks
  const int v_s[4] = {0, 0, 1, 1};   // values : Vf, Vf, Vs, Vs

  const unsigned short* __restrict__ Ah =
      qk + (size_t)(a_s[ty] * 2 + 0) * SLE + (size_t)slice * NSL;
  const unsigned short* __restrict__ Al =
      qk + (size_t)(a_s[ty] * 2 + 1) * SLE + (size_t)slice * NSL;
  const unsigned short* __restrict__ Kh_ =
      qk + (size_t)(b_s[ty] * 2 + 0) * SLE + (size_t)slice * NSL;
  const unsigned short* __restrict__ Kl_ =
      qk + (size_t)(b_s[ty] * 2 + 1) * SLE + (size_t)slice * NSL;
  const unsigned short* __restrict__ Vt_ =
      vt + (size_t)v_s[ty] * SLE + (size_t)slice * NSL;

  const int tid  = threadIdx.x;
  const int wave = tid >> 6;
  const int lane = tid & 63;
  const int hi   = lane >> 5;
  const int ql   = lane & 31;
  const int q0   = wave * 64;
  const int d15  = ql & 15;

  const float SC = 0.25f * 1.4426950408889634f;  // 1/sqrt(D) * log2(e)

  // Q fragments (B-operand): lane(ql,hi) holds Q[q0+qt*32+ql][hi*8+j]
  bf16x8 qh[2], qlo[2];
  #pragma unroll
  for (int qt = 0; qt < 2; ++qt) {
    const int qrow = q0 + qt * 32 + ql;
    qh[qt]  = *(const bf16x8*)&Ah[qrow * 16 + hi * 8];
    qlo[qt] = *(const bf16x8*)&Al[qrow * 16 + hi * 8];
  }

  f32x16 Z;
  #pragma unroll
  for (int r = 0; r < 16; ++r) Z[r] = 0.0f;

  f32x16 o[2];
  float  l_[2] = {0.0f, 0.0f};
  float  m_[2];
  m_[0] = m_[1] = (ty == 1) ? -1e30f : 0.0f;
  #pragma unroll
  for (int qt = 0; qt < 2; ++qt)
    #pragma unroll
    for (int r = 0; r < 16; ++r) o[qt][r] = 0.0f;

  for (int kc = 0; kc < Nn; kc += 32) {
    const int krow = kc + ql;
    const bf16x8 kh = *(const bf16x8*)&Kh_[krow * 16 + hi * 8];
    const bf16x8 kl = *(const bf16x8*)&Kl_[krow * 16 + hi * 8];
    // V fragments (B-operand): lane(ql,hi) holds V[kc+ks*16+hi*8+j][d15]
    const bf16x8 vb0 = *(const bf16x8*)&Vt_[d15 * 512 + kc + hi * 8];
    const bf16x8 vb1 = *(const bf16x8*)&Vt_[d15 * 512 + kc + 16 + hi * 8];

    #pragma unroll
    for (int qt = 0; qt < 2; ++qt) {
      f32x16 S;
      S = __builtin_amdgcn_mfma_f32_32x32x16_bf16(kh, qh[qt],  Z, 0, 0, 0);
      S = __builtin_amdgcn_mfma_f32_32x32x16_bf16(kh, qlo[qt], S, 0, 0, 0);
      S = __builtin_amdgcn_mfma_f32_32x32x16_bf16(kl, qh[qt],  S, 0, 0, 0);
      if (ty == 1)
        S = __builtin_amdgcn_mfma_f32_32x32x16_bf16(kl, qlo[qt], S, 0, 0, 0);

      if (ty == 1) {
        // deferred-rescale online max (T13), uniform across half-waves
        float smax = S[0];
        #pragma unroll
        for (int r = 1; r < 16; ++r) smax = fmaxf(smax, S[r]);
        float cm = smax * SC;
        cm = fmaxf(cm, __shfl_xor(cm, 32));
        if (!__all(cm <= m_[qt] + 8.0f)) {
          const float nm = fmaxf(m_[qt], cm);
          const float f  = exp2f(m_[qt] - nm);
          l_[qt] *= f;
          #pragma unroll
          for (int r = 0; r < 16; ++r) {
            const int qloc = (r & 3) + 8 * (r >> 2) + 4 * hi;
            o[qt][r] *= __shfl(f, qloc);
          }
          m_[qt] = nm;
        }
      }

      float p[16];
      float ls = 0.0f;
      #pragma unroll
      for (int r = 0; r < 16; ++r) {
        p[r] = exp2f(fmaf(S[r], SC, -m_[qt]));
        ls += p[r];
      }
      l_[qt] += ls;

      // repack P (rows k, col q=ql) into PV A-fragment (row q=ql, k along j)
      FragU pa0, pa1;
      {
        const unsigned wa = pk_bf16(p[0],  p[1]);
        const unsigned wb = pk_bf16(p[2],  p[3]);
        const unsigned wc = pk_bf16(p[4],  p[5]);
        const unsigned wd = pk_bf16(p[6],  p[7]);
        const unsigned swa = __shfl_xor(wa, 32);
        const unsigned swb = __shfl_xor(wb, 32);
        const unsigned swc = __shfl_xor(wc, 32);
        const unsigned swd = __shfl_xor(wd, 32);
        pa0.u[0] = hi ? swc : wa;
        pa0.u[1] = hi ? swd : wb;
        pa0.u[2] = hi ? wc  : swa;
        pa0.u[3] = hi ? wd  : swb;
        const unsigned we = pk_bf16(p[8],  p[9]);
        const unsigned wf_ = pk_bf16(p[10], p[11]);
        const unsigned wg = pk_bf16(p[12], p[13]);
        const unsigned wh = pk_bf16(p[14], p[15]);
        const unsigned swe = __shfl_xor(we, 32);
        const unsigned swf = __shfl_xor(wf_, 32);
        const unsigned swg = __shfl_xor(wg, 32);
        const unsigned swh = __shfl_xor(wh, 32);
        pa1.u[0] = hi ? swg : we;
        pa1.u[1] = hi ? swh : wf_;
        pa1.u[2] = hi ? wg  : swe;
        pa1.u[3] = hi ? wh  : swf;
      }
      o[qt] = __builtin_amdgcn_mfma_f32_32x32x16_bf16(pa0.v, vb0, o[qt], 0, 0, 0);
      o[qt] = __builtin_amdgcn_mfma_f32_32x32x16_bf16(pa1.v, vb1, o[qt], 0, 0, 0);
    }
  }

  // epilogue: merge l across half-waves, normalize, store (validated)
  const int b = slice / (Hh * Tt);
  const int h = (slice / Tt) % Hh;
  const int t = slice % Tt;
  float* __restrict__ outp = ctx + (size_t)ty * PROJ;
  #pragma unroll
  for (int qt = 0; qt < 2; ++qt) {
    const float lsum = l_[qt] + __shfl_xor(l_[qt], 32);
    const float linv = 1.0f / lsum;
    #pragma unroll
    for (int r = 0; r < 16; ++r) {
      const int qloc = (r & 3) + 8 * (r >> 2) + 4 * hi;
      const float lr = __shfl(linv, qloc);
      if (ql < 16) {
        const int n = q0 + qt * 32 + qloc;
        outp[(((size_t)b * Nn + n) * Tt + t) * Ee + h * Dd + ql] = o[qt][r] * lr;
      }
    }
  }
}

// ---------------------------------------------------------------------------
// out_mfma: out[ty] = ctx[ty] @ Wout + bout  (MFMA, 3-term inline split)
// ---------------------------------------------------------------------------
__global__ __launch_bounds__(256) void out_mfma_kernel(
    const float* __restrict__ ctx, const unsigned short* __restrict__ wf,
    const float* __restrict__ bout, float* __restrict__ out)
{
  const int ty   = blockIdx.y;
  const int tok0 = blockIdx.x * 32;
  const int wave = threadIdx.x >> 6;
  const int lane = threadIdx.x & 63;
  const int ql = lane & 31, hi = lane >> 5;

  f32x16 acc;
  #pragma unroll
  for (int r = 0; r < 16; ++r) acc[r] = 0.f;

  const float* __restrict__ xrow =
      ctx + (size_t)ty * PROJ + (size_t)(tok0 + ql) * Ee;
  const unsigned short* __restrict__ wbase =
      wf + ((size_t)(6 * 2) * 2048 + wave * 512 + lane) * 8;

  for (int ks = 0; ks < 8; ++ks) {
    const float4 a0 = *(const float4*)&xrow[ks * 16 + hi * 8];
    const float4 a1 = *(const float4*)&xrow[ks * 16 + hi * 8 + 4];
    float e8[8] = {a0.x, a0.y, a0.z, a0.w, a1.x, a1.y, a1.z, a1.w};
    bf16x8 xh, xl;
    split_frag(e8, xh, xl);
    const bf16x8 wh = *(const bf16x8*)&wbase[(size_t)ks * 512];
    const bf16x8 wl = *(const bf16x8*)&wbase[(size_t)ks * 512 + 2048 * 8];
    acc = __builtin_amdgcn_mfma_f32_32x32x16_bf16(xh, wh, acc, 0, 0, 0);
    acc = __builtin_amdgcn_mfma_f32_32x32x16_bf16(xh, wl, acc, 0, 0, 0);
    acc = __builtin_amdgcn_mfma_f32_32x32x16_bf16(xl, wh, acc, 0, 0, 0);
  }

  const int c = wave * 32 + ql;
  const float bc = bout[c];
  #pragma unroll
  for (int r = 0; r < 16; ++r) {
    const int tok = tok0 + (r & 3) + 8 * (r >> 2) + 4 * hi;
    out[(size_t)ty * PROJ + (size_t)tok * Ee + c] = acc[r] + bc;
  }
}

// ---------------------------------------------------------------------------
extern "C" void kernel_launch(void* const* d_in, const int* in_sizes, int n_in,
                              void* d_out, int out_size, void* d_ws, size_t ws_size,
                              hipStream_t stream) {
  const float* fq  = (const float*)d_in[0];
  const float* fk  = (const float*)d_in[1];
  const float* fv  = (const float*)d_in[2];
  const float* sq  = (const float*)d_in[3];
  const float* sk  = (const float*)d_in[4];
  const float* sv  = (const float*)d_in[5];
  const float* WfQ = (const float*)d_in[6];
  const float* WfK = (const float*)d_in[7];
  const float* WfV = (const float*)d_in[8];
  const float* WsQ = (const float*)d_in[9];
  const float* WsK = (const float*)d_in[10];
  const float* WsV = (const float*)d_in[11];
  const float* Kj  = (const float*)d_in[12];
  const float* Vfp = (const float*)d_in[13];
  const float* Wout = (const float*)d_in[14];
  const float* bout = (const float*)d_in[15];

  unsigned short* qk = (unsigned short*)d_ws;          // 10 * SLE ushorts
  unsigned short* vt = qk + (size_t)10 * SLE;          // 2 * SLE ushorts
  unsigned short* wf = vt + (size_t)2 * SLE;           // 7*2*2048*8 = 229376
  float* ctx = (float*)(wf + 229376);                  // 4 * PROJ floats

  PtrPack pp;
  pp.x[0] = fq; pp.x[1] = fk; pp.x[2] = fv;
  pp.x[3] = sq; pp.x[4] = sk; pp.x[5] = sv;
  pp.W[0] = WfQ; pp.W[1] = WfK; pp.W[2] = WfV;
  pp.W[3] = WsQ; pp.W[4] = WsK; pp.W[5] = WsV;
  WPack wp;
  wp.W[0] = WfQ; wp.W[1] = WfK; wp.W[2] = WfV;
  wp.W[3] = WsQ; wp.W[4] = WsK; wp.W[5] = WsV; wp.W[6] = Wout;

  prep_w_kernel<<<7, 256, 0, stream>>>(wp, wf);
  proj_mfma_kernel<<<dim3(384, 6), 256, 0, stream>>>(pp, Kj, Vfp, qk, vt, wf);
  attn_mfma_kernel<<<dim3(SLICES, 4), 512, 0, stream>>>(qk, vt, ctx);
  out_mfma_kernel<<<dim3(NTOK / 32, 4), 256, 0, stream>>>(ctx, wf, bout, (float*)d_out);
}

// Round 7
// 195.090 us; speedup vs baseline: 2.2955x; 1.1736x over previous
//
#include <hip/hip_runtime.h>
#include <math.h>

// Dims (fixed by the problem)
constexpr int Bb = 2, Nn = 512, Tt = 12, Ee = 128, Hh = 8, Dd = 16;
constexpr int NTOK   = Bb * Nn * Tt;      // 12288 tokens
constexpr int PROJ   = NTOK * Ee;         // 1572864 floats per [B,N,T,E] tensor
constexpr int SLICES = Bb * Hh * Tt;      // 192 attention slices
constexpr int NSL    = Nn * Dd;           // 8192 elems per (slice, qk tensor)
constexpr long SLE   = (long)SLICES * NSL;
constexpr int NSL17  = 17 * 512;          // vt per-slice stride (d=16 -> ones row)
constexpr long SLE17 = (long)SLICES * NSL17;

// Workspace layout:
//   qk  : 5 QK-role tensors x {hi,lo} bf16 [s][hl][slice][n][d], PRE-SCALED
//         by sqrt(1/4*log2e); compact s: 0=Qf 1=Kf 2=Qs 3=Ks 4=Qfs (30MB)
//   vt  : 2 V tensors bf16 transposed [s][slice][d(17)][n]; d=16 row = 1.0
//   wf  : 7 weight mats x {hi,lo} in B-fragment layout (QK weights scaled)
//   ctx : 4 attention outputs fp32 token-major [B,N,T,E]

struct PtrPack { const float* x[6]; const float* W[6]; };
struct WPack   { const float* W[7]; };

typedef __attribute__((ext_vector_type(8)))  short bf16x8;
typedef __attribute__((ext_vector_type(16))) float f32x16;
union FragU { bf16x8 v; unsigned u[4]; };

__device__ __forceinline__ unsigned pk_bf16(float a, float b) {
  unsigned r;
  asm("v_cvt_pk_bf16_f32 %0, %1, %2" : "=v"(r) : "v"(a), "v"(b));
  return r;
}
// fp32 -> bf16 hi + bf16 residual-lo fragments (8 elems)
__device__ __forceinline__ void split_frag(const float e[8], bf16x8& hv, bf16x8& lv) {
  FragU H, L;
  #pragma unroll
  for (int i = 0; i < 4; ++i) {
    const unsigned h = pk_bf16(e[2*i], e[2*i+1]);
    const float h0 = __uint_as_float(h << 16);
    const float h1 = __uint_as_float(h & 0xffff0000u);
    L.u[i] = pk_bf16(e[2*i] - h0, e[2*i+1] - h1);
    H.u[i] = h;
  }
  hv = H.v; lv = L.v;
}

// ---------------------------------------------------------------------------
// prep_w: split 7 weight matrices into hi/lo bf16 B-operand fragments.
// QK-role weights (WfQ,WfK,WsQ,WsK) pre-scaled by sqrt(0.25*log2e) so every
// QK^T product lands already in exp2-domain units.
// ---------------------------------------------------------------------------
__global__ __launch_bounds__(256) void prep_w_kernel(
    WPack wp, unsigned short* __restrict__ wf)
{
  const int m = blockIdx.x;
  const float SQ = sqrtf(0.25f * 1.4426950408889634f);
  const float scale = (m == 0 || m == 1 || m == 3 || m == 4) ? SQ : 1.0f;
  const float* __restrict__ W = wp.W[m];
  for (int e = threadIdx.x; e < 2048; e += 256) {
    const int ct = e >> 9, ks = (e >> 6) & 7, lane = e & 63;
    const int ql = lane & 31, hi = lane >> 5;
    const int c = ct * 32 + ql, k0 = ks * 16 + hi * 8;
    float w[8];
    #pragma unroll
    for (int j = 0; j < 8; ++j) w[j] = W[(size_t)(k0 + j) * Ee + c] * scale;
    bf16x8 hv, lv;
    split_frag(w, hv, lv);
    *(bf16x8*)&wf[((size_t)(m * 2 + 0) * 2048 + e) * 8] = hv;
    *(bf16x8*)&wf[((size_t)(m * 2 + 1) * 2048 + e) * 8] = lv;
  }
}

// ---------------------------------------------------------------------------
// proj_mfma: y = x @ W' via 32x32x16 bf16 MFMA, 3-term hi/lo split (4-term
// for ty==3).  Block = (b, t, n-chunk of 32).  x tile staged global->LDS
// coalesced (rows are 512B contiguous); fragments read from LDS; C staged
// back through the same LDS buffer; epilogue writes attn-ready operands
// coalesced.  ty 2/5 (V): transposed [slice][d][n] + ones row at d=16.
// ---------------------------------------------------------------------------
__global__ __launch_bounds__(256) void proj_mfma_kernel(
    PtrPack pp, const float* __restrict__ Kj, const float* __restrict__ Vfp,
    unsigned short* __restrict__ qk, unsigned short* __restrict__ vt,
    const unsigned short* __restrict__ wf)
{
  __shared__ float XS[32][132];
  const int ty = blockIdx.y;
  const int g  = blockIdx.x;          // (bt<<4) | nc
  const int nc = g & 15;
  const int bt = g >> 4;              // 0..23
  const int b  = bt / Tt, t = bt % Tt;
  const int n0 = nc * 32;
  const int tid = threadIdx.x;
  const int wave = tid >> 6, lane = tid & 63;
  const int ql = lane & 31, hi = lane >> 5;

  // stage x tile (32 rows x 512B, coalesced)
  const float* __restrict__ xg = pp.x[ty];
  for (int i = tid; i < 1024; i += 256) {
    const int row = i >> 5, ch = i & 31;
    *(float4*)&XS[row][ch * 4] =
        *(const float4*)&xg[((size_t)(b * Nn + n0 + row) * Tt + t) * Ee + ch * 4];
  }
  __syncthreads();

  f32x16 acc;
  #pragma unroll
  for (int r = 0; r < 16; ++r) acc[r] = 0.f;

  const unsigned short* __restrict__ wbase =
      wf + ((size_t)(ty * 2) * 2048 + wave * 512 + lane) * 8;

  for (int ks = 0; ks < 8; ++ks) {
    float e8[8];
    *(float4*)&e8[0] = *(const float4*)&XS[ql][ks * 16 + hi * 8];
    *(float4*)&e8[4] = *(const float4*)&XS[ql][ks * 16 + hi * 8 + 4];
    bf16x8 xh, xl;
    split_frag(e8, xh, xl);
    const bf16x8 wh = *(const bf16x8*)&wbase[(size_t)ks * 512];
    const bf16x8 wl = *(const bf16x8*)&wbase[(size_t)ks * 512 + 2048 * 8];
    acc = __builtin_amdgcn_mfma_f32_32x32x16_bf16(xh, wh, acc, 0, 0, 0);
    acc = __builtin_amdgcn_mfma_f32_32x32x16_bf16(xh, wl, acc, 0, 0, 0);
    acc = __builtin_amdgcn_mfma_f32_32x32x16_bf16(xl, wh, acc, 0, 0, 0);
    if (ty == 3)
      acc = __builtin_amdgcn_mfma_f32_32x32x16_bf16(xl, wl, acc, 0, 0, 0);
  }
  __syncthreads();   // done reading x tile

  // stage C tile: row = n-offset qloc(r,hi), col = wave*32+ql
  #pragma unroll
  for (int r = 0; r < 16; ++r)
    XS[(r & 3) + 8 * (r >> 2) + 4 * hi][wave * 32 + ql] = acc[r];
  __syncthreads();

  if (ty == 2 || ty == 5) {           // V tensors -> transposed [slice][d][n]
    if (tid < 128) {
      const int h = tid >> 4, d = tid & 15;
      const int slice = (b * Hh + h) * Tt + t;
      const long vsel = (ty == 5);
      float v[32];
      #pragma unroll
      for (int n = 0; n < 32; ++n) v[n] = XS[n][h * 16 + d];
      FragU F[4];
      #pragma unroll
      for (int i = 0; i < 16; ++i)
        F[i >> 2].u[i & 3] = pk_bf16(v[2 * i], v[2 * i + 1]);
      unsigned short* __restrict__ dst =
          vt + vsel * SLE17 + (size_t)slice * NSL17 + d * 512 + n0;
      #pragma unroll
      for (int i = 0; i < 4; ++i) *(bf16x8*)&dst[i * 8] = F[i].v;
      if (d == 0) {                   // ones row (d=16) for the l-column trick
        FragU O_;
        #pragma unroll
        for (int i = 0; i < 4; ++i) O_.u[i] = 0x3F803F80u;
        unsigned short* __restrict__ op =
            vt + vsel * SLE17 + (size_t)slice * NSL17 + 16 * 512 + n0;
        #pragma unroll
        for (int i = 0; i < 4; ++i) *(bf16x8*)&op[i * 8] = O_.v;
      }
    }
  } else {                            // QK-role tensors -> hi/lo planes
    const int h = tid >> 5, nn = tid & 31;
    const int slice = (b * Hh + h) * Tt + t;
    const int n = n0 + nn;
    float v[16];
    #pragma unroll
    for (int d = 0; d < 16; ++d) v[d] = XS[nn][h * 16 + d];
    FragU HI[2], LO[2];
    #pragma unroll
    for (int i = 0; i < 8; ++i) {
      const unsigned hw = pk_bf16(v[2 * i], v[2 * i + 1]);
      const float h0 = __uint_as_float(hw << 16);
      const float h1 = __uint_as_float(hw & 0xffff0000u);
      HI[i >> 2].u[i & 3] = hw;
      LO[i >> 2].u[i & 3] = pk_bf16(v[2 * i] - h0, v[2 * i + 1] - h1);
    }
    const int s = (ty == 0) ? 0 : (ty == 1) ? 1 : (ty == 3) ? 2 : 3;
    unsigned short* __restrict__ hp =
        qk + (size_t)(s * 2 + 0) * SLE + (size_t)slice * NSL + n * 16;
    unsigned short* __restrict__ lp =
        qk + (size_t)(s * 2 + 1) * SLE + (size_t)slice * NSL + n * 16;
    *(bf16x8*)&hp[0] = HI[0].v;  *(bf16x8*)&hp[8] = HI[1].v;
    *(bf16x8*)&lp[0] = LO[0].v;  *(bf16x8*)&lp[8] = LO[1].v;
    if (ty == 3) {                    // FlowSpeed: v = Qs*SQ -> Qfs*SQ (s=4)
      const float SQ  = sqrtf(0.25f * 1.4426950408889634f);
      const float RSQ = 1.0f / SQ;
      const float kj = Kj[n];
      const float iv = 1.0f / (Vfp[n] + 1e-5f);
      float gv[16];
      #pragma unroll
      for (int d = 0; d < 16; ++d) {
        const float vq = v[d] * RSQ;
        gv[d] = SQ * (kj * (vq - vq * vq * iv));
      }
      FragU GH[2], GL[2];
      #pragma unroll
      for (int i = 0; i < 8; ++i) {
        const unsigned hw = pk_bf16(gv[2 * i], gv[2 * i + 1]);
        const float h0 = __uint_as_float(hw << 16);
        const float h1 = __uint_as_float(hw & 0xffff0000u);
        GH[i >> 2].u[i & 3] = hw;
        GL[i >> 2].u[i & 3] = pk_bf16(gv[2 * i] - h0, gv[2 * i + 1] - h1);
      }
      unsigned short* __restrict__ gp =
          qk + (size_t)(4 * 2 + 0) * SLE + (size_t)slice * NSL + n * 16;
      unsigned short* __restrict__ glp =
          qk + (size_t)(4 * 2 + 1) * SLE + (size_t)slice * NSL + n * 16;
      *(bf16x8*)&gp[0]  = GH[0].v;  *(bf16x8*)&gp[8]  = GH[1].v;
      *(bf16x8*)&glp[0] = GL[0].v;  *(bf16x8*)&glp[8] = GL[1].v;
    }
  }
}

// ---------------------------------------------------------------------------
// attn: MFMA flash attention.  Operands pre-scaled -> S is already the exp2
// argument; p = exp2_raw(S) (ty!=1) or exp2_raw(S-m) with deferred-rescale
// online max (ty==1, arg bounded <= 8 structurally).  V has a ones-row at
// d=16 -> PV columns 16..31 accumulate l for free; epilogue normalizes via
// per-row broadcast + v_rcp.
// ---------------------------------------------------------------------------
__global__ __launch_bounds__(512) void attn_mfma_kernel(
    const unsigned short* __restrict__ qk, const unsigned short* __restrict__ vt,
    float* __restrict__ ctx)
{
  const int slice = blockIdx.x;
  const int ty    = blockIdx.y;
  const int a_s[4] = {0, 1, 3, 2};   // queries: Qf, Kf, Ks, Qs
  const int b_s[4] = {1, 4, 0, 3};   // keys   : Kf, Qfs, Qf, Ks
  const int v_s[4] = {0, 0, 1, 1};   // values : Vf, Vf, Vs, Vs

  const unsigned short* __restrict__ Ah =
      qk + (size_t)(a_s[ty] * 2 + 0) * SLE + (size_t)slice * NSL;
  const unsigned short* __restrict__ Al =
      qk + (size_t)(a_s[ty] * 2 + 1) * SLE + (size_t)slice * NSL;
  const unsigned short* __restrict__ Kh_ =
      qk + (size_t)(b_s[ty] * 2 + 0) * SLE + (size_t)slice * NSL;
  const unsigned short* __restrict__ Kl_ =
      qk + (size_t)(b_s[ty] * 2 + 1) * SLE + (size_t)slice * NSL;
  const unsigned short* __restrict__ Vt_ =
      vt + (size_t)v_s[ty] * SLE17 + (size_t)slice * NSL17;

  const int tid  = threadIdx.x;
  const int wave = tid >> 6;
  const int lane = tid & 63;
  const int hi   = lane >> 5;
  const int ql   = lane & 31;
  const int q0   = wave * 64;
  const int dv   = (ql < 16) ? ql : 16;   // lanes 16-31 -> ones row (l column)
  const unsigned short* __restrict__ vbase = Vt_ + dv * 512;

  // Q fragments (B-operand): lane(ql,hi) holds Q[q0+qt*32+ql][hi*8+j]
  bf16x8 qh[2], qlo[2];
  #pragma unroll
  for (int qt = 0; qt < 2; ++qt) {
    const int qrow = q0 + qt * 32 + ql;
    qh[qt]  = *(const bf16x8*)&Ah[qrow * 16 + hi * 8];
    qlo[qt] = *(const bf16x8*)&Al[qrow * 16 + hi * 8];
  }

  f32x16 Z;
  #pragma unroll
  for (int r = 0; r < 16; ++r) Z[r] = 0.0f;

  f32x16 o[2];
  float  m_[2] = {-1e30f, -1e30f};
  #pragma unroll
  for (int qt = 0; qt < 2; ++qt)
    #pragma unroll
    for (int r = 0; r < 16; ++r) o[qt][r] = 0.0f;

  for (int kc = 0; kc < Nn; kc += 32) {
    const int krow = kc + ql;
    const bf16x8 kh = *(const bf16x8*)&Kh_[krow * 16 + hi * 8];
    const bf16x8 kl = *(const bf16x8*)&Kl_[krow * 16 + hi * 8];
    const bf16x8 vb0 = *(const bf16x8*)&vbase[kc + hi * 8];
    const bf16x8 vb1 = *(const bf16x8*)&vbase[kc + 16 + hi * 8];

    #pragma unroll
    for (int qt = 0; qt < 2; ++qt) {
      f32x16 S;
      S = __builtin_amdgcn_mfma_f32_32x32x16_bf16(kh, qh[qt],  Z, 0, 0, 0);
      S = __builtin_amdgcn_mfma_f32_32x32x16_bf16(kh, qlo[qt], S, 0, 0, 0);
      S = __builtin_amdgcn_mfma_f32_32x32x16_bf16(kl, qh[qt],  S, 0, 0, 0);
      if (ty == 1)
        S = __builtin_amdgcn_mfma_f32_32x32x16_bf16(kl, qlo[qt], S, 0, 0, 0);

      float p[16];
      if (ty == 1) {
        // deferred-rescale online max: per-query max across both halves
        float smax = S[0];
        #pragma unroll
        for (int r = 1; r < 16; ++r) smax = fmaxf(smax, S[r]);
        float cm = fmaxf(smax, __shfl_xor(smax, 32));
        if (!__all(cm <= m_[qt] + 8.0f)) {
          const float nm = fmaxf(m_[qt], cm);
          const float f  = __builtin_amdgcn_exp2f(m_[qt] - nm);
          #pragma unroll
          for (int r = 0; r < 16; ++r) {
            const int qloc = (r & 3) + 8 * (r >> 2) + 4 * hi;
            o[qt][r] *= __shfl(f, qloc);   // rescales l column too
          }
          m_[qt] = nm;
        }
        #pragma unroll
        for (int r = 0; r < 16; ++r)
          p[r] = __builtin_amdgcn_exp2f(S[r] - m_[qt]);
      } else {
        #pragma unroll
        for (int r = 0; r < 16; ++r)
          p[r] = __builtin_amdgcn_exp2f(S[r]);
      }

      // repack P (rows k, col q=ql) into PV A-fragment (row q=ql, k along j)
      FragU pa0, pa1;
      {
        const unsigned wa = pk_bf16(p[0],  p[1]);
        const unsigned wb = pk_bf16(p[2],  p[3]);
        const unsigned wc = pk_bf16(p[4],  p[5]);
        const unsigned wd = pk_bf16(p[6],  p[7]);
        const unsigned swa = __shfl_xor(wa, 32);
        const unsigned swb = __shfl_xor(wb, 32);
        const unsigned swc = __shfl_xor(wc, 32);
        const unsigned swd = __shfl_xor(wd, 32);
        pa0.u[0] = hi ? swc : wa;
        pa0.u[1] = hi ? swd : wb;
        pa0.u[2] = hi ? wc  : swa;
        pa0.u[3] = hi ? wd  : swb;
        const unsigned we = pk_bf16(p[8],  p[9]);
        const unsigned wf_ = pk_bf16(p[10], p[11]);
        const unsigned wg = pk_bf16(p[12], p[13]);
        const unsigned wh = pk_bf16(p[14], p[15]);
        const unsigned swe = __shfl_xor(we, 32);
        const unsigned swf = __shfl_xor(wf_, 32);
        const unsigned swg = __shfl_xor(wg, 32);
        const unsigned swh = __shfl_xor(wh, 32);
        pa1.u[0] = hi ? swg : we;
        pa1.u[1] = hi ? swh : wf_;
        pa1.u[2] = hi ? wg  : swe;
        pa1.u[3] = hi ? wh  : swf;
      }
      o[qt] = __builtin_amdgcn_mfma_f32_32x32x16_bf16(pa0.v, vb0, o[qt], 0, 0, 0);
      o[qt] = __builtin_amdgcn_mfma_f32_32x32x16_bf16(pa1.v, vb1, o[qt], 0, 0, 0);
    }
  }

  // epilogue: l lives in column 16 (lanes 16 / 48); normalize + store
  const int b = slice / (Hh * Tt);
  const int h = (slice / Tt) % Hh;
  const int t = slice % Tt;
  float* __restrict__ outp = ctx + (size_t)ty * PROJ;
  const int lsrc = (lane & 32) | 16;
  #pragma unroll
  for (int qt = 0; qt < 2; ++qt) {
    #pragma unroll
    for (int r = 0; r < 16; ++r) {
      const int qloc = (r & 3) + 8 * (r >> 2) + 4 * hi;
      const float lsum = __shfl(o[qt][r], lsrc);
      if (ql < 16) {
        const int n = q0 + qt * 32 + qloc;
        outp[(((size_t)b * Nn + n) * Tt + t) * Ee + h * Dd + ql] =
            o[qt][r] * __builtin_amdgcn_rcpf(lsum);
      }
    }
  }
}

// ---------------------------------------------------------------------------
// out_mfma: out[ty] = ctx[ty] @ Wout + bout.  ctx tile is contiguous 16KB ->
// staged through LDS both directions; fully coalesced float4 global traffic.
// ---------------------------------------------------------------------------
__global__ __launch_bounds__(256) void out_mfma_kernel(
    const float* __restrict__ ctx, const unsigned short* __restrict__ wf,
    const float* __restrict__ bout, float* __restrict__ out)
{
  __shared__ float XS[32][132];
  const int ty   = blockIdx.y;
  const int tok0 = blockIdx.x * 32;
  const int tid  = threadIdx.x;
  const int wave = tid >> 6, lane = tid & 63;
  const int ql = lane & 31, hi = lane >> 5;

  const float* __restrict__ src = ctx + (size_t)ty * PROJ + (size_t)tok0 * Ee;
  for (int i = tid; i < 1024; i += 256)
    *(float4*)&XS[i >> 5][(i & 31) * 4] = *(const float4*)&src[i * 4];
  __syncthreads();

  f32x16 acc;
  #pragma unroll
  for (int r = 0; r < 16; ++r) acc[r] = 0.f;

  const unsigned short* __restrict__ wbase =
      wf + ((size_t)(6 * 2) * 2048 + wave * 512 + lane) * 8;

  for (int ks = 0; ks < 8; ++ks) {
    float e8[8];
    *(float4*)&e8[0] = *(const float4*)&XS[ql][ks * 16 + hi * 8];
    *(float4*)&e8[4] = *(const float4*)&XS[ql][ks * 16 + hi * 8 + 4];
    bf16x8 xh, xl;
    split_frag(e8, xh, xl);
    const bf16x8 wh = *(const bf16x8*)&wbase[(size_t)ks * 512];
    const bf16x8 wl = *(const bf16x8*)&wbase[(size_t)ks * 512 + 2048 * 8];
    acc = __builtin_amdgcn_mfma_f32_32x32x16_bf16(xh, wh, acc, 0, 0, 0);
    acc = __builtin_amdgcn_mfma_f32_32x32x16_bf16(xh, wl, acc, 0, 0, 0);
    acc = __builtin_amdgcn_mfma_f32_32x32x16_bf16(xl, wh, acc, 0, 0, 0);
  }
  __syncthreads();

  #pragma unroll
  for (int r = 0; r < 16; ++r)
    XS[(r & 3) + 8 * (r >> 2) + 4 * hi][wave * 32 + ql] = acc[r];
  __syncthreads();

  float* __restrict__ dst = out + (size_t)ty * PROJ + (size_t)tok0 * Ee;
  for (int i = tid; i < 1024; i += 256) {
    const int row = i >> 5, c4 = (i & 31) * 4;
    float4 v = *(float4*)&XS[row][c4];
    const float4 bv = *(const float4*)&bout[c4];
    v.x += bv.x; v.y += bv.y; v.z += bv.z; v.w += bv.w;
    *(float4*)&dst[i * 4] = v;
  }
}

// ---------------------------------------------------------------------------
extern "C" void kernel_launch(void* const* d_in, const int* in_sizes, int n_in,
                              void* d_out, int out_size, void* d_ws, size_t ws_size,
                              hipStream_t stream) {
  const float* fq  = (const float*)d_in[0];
  const float* fk  = (const float*)d_in[1];
  const float* fv  = (const float*)d_in[2];
  const float* sq  = (const float*)d_in[3];
  const float* sk  = (const float*)d_in[4];
  const float* sv  = (const float*)d_in[5];
  const float* WfQ = (const float*)d_in[6];
  const float* WfK = (const float*)d_in[7];
  const float* WfV = (const float*)d_in[8];
  const float* WsQ = (const float*)d_in[9];
  const float* WsK = (const float*)d_in[10];
  const float* WsV = (const float*)d_in[11];
  const float* Kj  = (const float*)d_in[12];
  const float* Vfp = (const float*)d_in[13];
  const float* Wout = (const float*)d_in[14];
  const float* bout = (const float*)d_in[15];

  unsigned short* qk = (unsigned short*)d_ws;          // 10 * SLE ushorts
  unsigned short* vt = qk + (size_t)10 * SLE;          // 2 * SLE17 ushorts
  unsigned short* wf = vt + (size_t)2 * SLE17;         // 7*2*2048*8 = 229376
  float* ctx = (float*)(wf + 229376);                  // 4 * PROJ floats

  PtrPack pp;
  pp.x[0] = fq; pp.x[1] = fk; pp.x[2] = fv;
  pp.x[3] = sq; pp.x[4] = sk; pp.x[5] = sv;
  pp.W[0] = WfQ; pp.W[1] = WfK; pp.W[2] = WfV;
  pp.W[3] = WsQ; pp.W[4] = WsK; pp.W[5] = WsV;
  WPack wp;
  wp.W[0] = WfQ; wp.W[1] = WfK; wp.W[2] = WfV;
  wp.W[3] = WsQ; wp.W[4] = WsK; wp.W[5] = WsV; wp.W[6] = Wout;

  prep_w_kernel<<<7, 256, 0, stream>>>(wp, wf);
  proj_mfma_kernel<<<dim3(384, 6), 256, 0, stream>>>(pp, Kj, Vfp, qk, vt, wf);
  attn_mfma_kernel<<<dim3(SLICES, 4), 512, 0, stream>>>(qk, vt, ctx);
  out_mfma_kernel<<<dim3(NTOK / 32, 4), 256, 0, stream>>>(ctx, wf, bout, (float*)d_out);
}